// Round 1
// baseline (924.564 us; speedup 1.0000x reference)
//
#include <hip/hip_runtime.h>
#include <math.h>

typedef __bf16 bf16;
typedef __bf16 bf16x8 __attribute__((ext_vector_type(8)));
typedef __bf16 bf16x4 __attribute__((ext_vector_type(4)));
typedef float  floatx4 __attribute__((ext_vector_type(4)));

#define MFMA16(a, b, c) __builtin_amdgcn_mfma_f32_16x16x32_bf16(a, b, c, 0, 0, 0)

static constexpr int S  = 2048;
static constexpr int DM = 1024;
static constexpr int Dh = 64;

// ---------------------------------------------------------------------------
// Pack queries|values|keys into one bf16 [8192][3072] buffer (X_all).
// Column order [q | v | k] so that V-GEMM (A = X_all+1024, K=2048) contracts
// over [values, keys] to match W_stack = [Wv_w ; Av@Bv].
// ---------------------------------------------------------------------------
__global__ __launch_bounds__(256) void prep_convert(
    const float* __restrict__ q, const float* __restrict__ k,
    const float* __restrict__ v, bf16* __restrict__ X)
{
  int s = blockIdx.x;
  int c = threadIdx.x * 4;
  size_t src = (size_t)s * DM + c;
  float4 qv = *(const float4*)(q + src);
  float4 vv = *(const float4*)(v + src);
  float4 kv = *(const float4*)(k + src);
  size_t dst = (size_t)s * (3 * DM);
  bf16x4 t;
  t[0] = (bf16)qv.x; t[1] = (bf16)qv.y; t[2] = (bf16)qv.z; t[3] = (bf16)qv.w;
  *(bf16x4*)(X + dst + c) = t;
  t[0] = (bf16)vv.x; t[1] = (bf16)vv.y; t[2] = (bf16)vv.z; t[3] = (bf16)vv.w;
  *(bf16x4*)(X + dst + DM + c) = t;
  t[0] = (bf16)kv.x; t[1] = (bf16)kv.y; t[2] = (bf16)kv.z; t[3] = (bf16)kv.w;
  *(bf16x4*)(X + dst + 2 * DM + c) = t;
}

// ---------------------------------------------------------------------------
// Fold LoRA into effective weights, store TRANSPOSED ([n][k], k contiguous)
// as bf16 for the GEMM B-operand. WvT is [1024][2048]: cols 0:1024 = Wv_w^T,
// cols 1024:2048 = (Av@Bv)^T.
// ---------------------------------------------------------------------------
__global__ __launch_bounds__(256) void fold_weights(
    const float* __restrict__ Wq, const float* __restrict__ Aq, const float* __restrict__ Bq,
    const float* __restrict__ Wk, const float* __restrict__ Ak, const float* __restrict__ Bk,
    const float* __restrict__ Wv, const float* __restrict__ Av, const float* __restrict__ Bv,
    const float* __restrict__ Wo,
    bf16* __restrict__ WqT, bf16* __restrict__ WkT,
    bf16* __restrict__ WvT, bf16* __restrict__ WoT)
{
  __shared__ float tile[32][33];
  const int tx = threadIdx.x, ty = threadIdx.y;  // block (32, 8)
  const int n0 = blockIdx.x * 32, k0 = blockIdx.y * 32;
  for (int mi = 0; mi < 5; ++mi) {
    #pragma unroll
    for (int i = 0; i < 4; ++i) {
      int k = k0 + ty + i * 8, n = n0 + tx;
      float val = 0.f;
      if (mi == 0) {
        val = Wq[(size_t)k * DM + n];
        #pragma unroll
        for (int r = 0; r < 8; ++r) val += Aq[k * 8 + r] * Bq[(size_t)r * DM + n];
      } else if (mi == 1) {
        val = Wk[(size_t)k * DM + n];
        #pragma unroll
        for (int r = 0; r < 8; ++r) val += Ak[k * 8 + r] * Bk[(size_t)r * DM + n];
      } else if (mi == 2) {
        val = Wv[(size_t)k * DM + n];
      } else if (mi == 3) {
        #pragma unroll
        for (int r = 0; r < 8; ++r) val += Av[k * 8 + r] * Bv[(size_t)r * DM + n];
      } else {
        val = Wo[(size_t)k * DM + n];
      }
      tile[ty + i * 8][tx] = val;
    }
    __syncthreads();
    #pragma unroll
    for (int i = 0; i < 4; ++i) {
      int n = n0 + ty + i * 8, k = k0 + tx;
      float val = tile[tx][ty + i * 8];
      if (mi == 0)      WqT[(size_t)n * DM + k] = (bf16)val;
      else if (mi == 1) WkT[(size_t)n * DM + k] = (bf16)val;
      else if (mi == 2) WvT[(size_t)n * 2048 + k] = (bf16)val;
      else if (mi == 3) WvT[(size_t)n * 2048 + 1024 + k] = (bf16)val;
      else              WoT[(size_t)n * DM + k] = (bf16)val;
    }
    __syncthreads();
  }
}

__global__ __launch_bounds__(256) void fold_bias(
    const float* __restrict__ Wqb, const float* __restrict__ Aqb,
    const float* __restrict__ BqW, const float* __restrict__ Bqb,
    const float* __restrict__ Wkb, const float* __restrict__ Akb,
    const float* __restrict__ BkW, const float* __restrict__ Bkb,
    const float* __restrict__ Wvb, const float* __restrict__ Avb,
    const float* __restrict__ BvW, const float* __restrict__ Bvb,
    const float* __restrict__ Wob,
    float* __restrict__ bq, float* __restrict__ bk,
    float* __restrict__ bv, float* __restrict__ bo)
{
  int n = blockIdx.x * 256 + threadIdx.x;
  float aq = Wqb[n] + Bqb[n];
  float ak = Wkb[n] + Bkb[n];
  float av = Wvb[n] + Bvb[n];
  #pragma unroll
  for (int r = 0; r < 8; ++r) {
    aq += Aqb[r] * BqW[(size_t)r * DM + n];
    ak += Akb[r] * BkW[(size_t)r * DM + n];
    av += Avb[r] * BvW[(size_t)r * DM + n];
  }
  bq[n] = aq; bk[n] = ak; bv[n] = av; bo[n] = Wob[n];
}

// ---------------------------------------------------------------------------
// 128x128-tile bf16 MFMA GEMM: C[M][N] = A[M][K] @ BT[N][K]^T + bias.
// mode 0: write fp32 row-major [M][N]
// mode 1: scatter bf16 to [b*16+h][s][d]   (Q/K heads layout)
// mode 2: scatter bf16 to [b*16+h][d][s]   (V transposed, for PV B-operand)
// ---------------------------------------------------------------------------
__global__ __launch_bounds__(256) void gemm_bf16(
    const bf16* __restrict__ A, int lda,
    const bf16* __restrict__ BT,
    const float* __restrict__ bias,
    int M, int N, int K,
    float* __restrict__ outF, bf16* __restrict__ outB, int mode)
{
  __shared__ bf16 sA[128][40];
  __shared__ bf16 sB[128][40];
  const int tid = threadIdx.x;
  const int bm0 = blockIdx.y * 128, bn0 = blockIdx.x * 128;
  const int w = tid >> 6, lane = tid & 63, lrow = lane & 15, quad = lane >> 4;
  const int wm = (w >> 1) * 64, wn = (w & 1) * 64;
  const int r0 = tid >> 2, seg = (tid & 3) * 8;

  const bf16* Ap0 = A + (size_t)(bm0 + r0) * lda + seg;
  const bf16* Ap1 = A + (size_t)(bm0 + r0 + 64) * lda + seg;
  const bf16* Bp0 = BT + (size_t)(bn0 + r0) * K + seg;
  const bf16* Bp1 = BT + (size_t)(bn0 + r0 + 64) * K + seg;

  floatx4 zero = {0.f, 0.f, 0.f, 0.f};
  floatx4 acc[4][4];
  #pragma unroll
  for (int i = 0; i < 4; ++i)
    #pragma unroll
    for (int j = 0; j < 4; ++j) acc[i][j] = zero;

  for (int kt = 0; kt < K; kt += 32) {
    bf16x8 a0 = *(const bf16x8*)(Ap0 + kt);
    bf16x8 a1 = *(const bf16x8*)(Ap1 + kt);
    bf16x8 b0 = *(const bf16x8*)(Bp0 + kt);
    bf16x8 b1 = *(const bf16x8*)(Bp1 + kt);
    __syncthreads();
    *(bf16x8*)&sA[r0][seg] = a0;
    *(bf16x8*)&sA[r0 + 64][seg] = a1;
    *(bf16x8*)&sB[r0][seg] = b0;
    *(bf16x8*)&sB[r0 + 64][seg] = b1;
    __syncthreads();
    bf16x8 aF[4], bF[4];
    #pragma unroll
    for (int i = 0; i < 4; ++i) aF[i] = *(const bf16x8*)&sA[wm + i * 16 + lrow][quad * 8];
    #pragma unroll
    for (int j = 0; j < 4; ++j) bF[j] = *(const bf16x8*)&sB[wn + j * 16 + lrow][quad * 8];
    #pragma unroll
    for (int i = 0; i < 4; ++i)
      #pragma unroll
      for (int j = 0; j < 4; ++j)
        acc[i][j] = MFMA16(aF[i], bF[j], acc[i][j]);
  }

  float bvs[4];
  #pragma unroll
  for (int j = 0; j < 4; ++j) bvs[j] = bias[bn0 + wn + j * 16 + lrow];

  #pragma unroll
  for (int i = 0; i < 4; ++i) {
    #pragma unroll
    for (int j = 0; j < 4; ++j) {
      #pragma unroll
      for (int r = 0; r < 4; ++r) {
        int gm = bm0 + wm + i * 16 + quad * 4 + r;   // C row  (m)
        int gn = bn0 + wn + j * 16 + lrow;           // C col  (n)
        float v = acc[i][j][r] + bvs[j];
        if (mode == 0) {
          outF[(size_t)gm * N + gn] = v;
        } else {
          int b = gm >> 11, s = gm & 2047, h = gn >> 6, d = gn & 63;
          size_t idx = (mode == 1)
            ? ((size_t)(b * 16 + h) * 2048 + s) * 64 + d
            : ((size_t)(b * 16 + h) * 64 + d) * 2048 + s;
          outB[idx] = (bf16)v;
        }
      }
    }
  }
}

// ---------------------------------------------------------------------------
// Pass 1: per-column (key-axis) softmax stats. Column c valid for rows q>=c.
// stats[bh][c] = (m[c], 1/(8*sum_q exp(s[q,c]-m[c])))
// Block: 64 columns (bh, c0). 4 waves stride over q-tiles of 16.
// ---------------------------------------------------------------------------
__global__ __launch_bounds__(256) void attn_pass1(
    const bf16* __restrict__ Qb, const bf16* __restrict__ Kb,
    float2* __restrict__ stats)
{
  const int bh = blockIdx.y;
  const int c0 = blockIdx.x * 64;
  const int tid = threadIdx.x;
  const int w = tid >> 6, lane = tid & 63, lrow = lane & 15, quad = lane >> 4;
  const bf16* Qh = Qb + (size_t)bh * S * Dh;
  const bf16* Kh = Kb + (size_t)bh * S * Dh;

  // K fragments (B-operand: n = lane&15 -> column, k = quad*8+j -> d) in regs
  bf16x8 kf[4][2];
  #pragma unroll
  for (int j = 0; j < 4; ++j) {
    const bf16* kp = Kh + (size_t)(c0 + j * 16 + lrow) * Dh + quad * 8;
    kf[j][0] = *(const bf16x8*)(kp);
    kf[j][1] = *(const bf16x8*)(kp + 32);
  }

  float rm[4], rs[4];
  #pragma unroll
  for (int j = 0; j < 4; ++j) { rm[j] = -INFINITY; rs[j] = 0.f; }

  for (int q0 = c0 + w * 16; q0 < S; q0 += 64) {
    const bf16* qp = Qh + (size_t)(q0 + lrow) * Dh + quad * 8;
    bf16x8 af0 = *(const bf16x8*)(qp);
    bf16x8 af1 = *(const bf16x8*)(qp + 32);
    const bool full = (q0 >= c0 + 63);   // every col <= c0+63 <= q0 <= q
    #pragma unroll
    for (int j = 0; j < 4; ++j) {
      floatx4 sacc = {0.f, 0.f, 0.f, 0.f};
      sacc = MFMA16(af0, kf[j][0], sacc);
      sacc = MFMA16(af1, kf[j][1], sacc);
      float v0 = sacc[0], v1 = sacc[1], v2 = sacc[2], v3 = sacc[3];
      if (!full) {
        int c = c0 + j * 16 + lrow;      // this lane's column (C/D col = lane&15)
        int qb = q0 + quad * 4;          // this lane's base row
        v0 = (qb + 0 >= c) ? v0 : -INFINITY;
        v1 = (qb + 1 >= c) ? v1 : -INFINITY;
        v2 = (qb + 2 >= c) ? v2 : -INFINITY;
        v3 = (qb + 3 >= c) ? v3 : -INFINITY;
      }
      float mt = fmaxf(fmaxf(v0, v1), fmaxf(v2, v3));
      float nm = fmaxf(rm[j], mt);
      if (nm > -INFINITY) {
        float corr = (rm[j] == -INFINITY) ? 0.f : __expf(rm[j] - nm);
        rs[j] = rs[j] * corr + __expf(v0 - nm) + __expf(v1 - nm)
                             + __expf(v2 - nm) + __expf(v3 - nm);
        rm[j] = nm;
      }
    }
  }

  // combine across the 4 quads (lanes L, L+16, L+32, L+48 share a column)
  #pragma unroll
  for (int j = 0; j < 4; ++j) {
    #pragma unroll
    for (int off = 16; off < 64; off <<= 1) {
      float om = __shfl_xor(rm[j], off, 64);
      float os = __shfl_xor(rs[j], off, 64);
      float nm = fmaxf(rm[j], om);
      float c1 = (rm[j] == -INFINITY) ? 0.f : __expf(rm[j] - nm);
      float c2 = (om == -INFINITY) ? 0.f : __expf(om - nm);
      rs[j] = rs[j] * c1 + os * c2;
      rm[j] = nm;
    }
  }

  __shared__ float smm[4][64];
  __shared__ float sms[4][64];
  if (lane < 16) {
    #pragma unroll
    for (int j = 0; j < 4; ++j) {
      smm[w][j * 16 + lane] = rm[j];
      sms[w][j * 16 + lane] = rs[j];
    }
  }
  __syncthreads();
  if (tid < 64) {
    float m = smm[0][tid], sum = sms[0][tid];
    #pragma unroll
    for (int ww = 1; ww < 4; ++ww) {
      float om = smm[ww][tid], os = sms[ww][tid];
      float nm = fmaxf(m, om);
      float c1 = (m == -INFINITY) ? 0.f : __expf(m - nm);
      float c2 = (om == -INFINITY) ? 0.f : __expf(om - nm);
      sum = sum * c1 + os * c2;
      m = nm;
    }
    stats[(size_t)bh * S + c0 + tid] = make_float2(m, 1.0f / (8.0f * sum));
  }
}

// ---------------------------------------------------------------------------
// Pass 2: out[q,:] = sum_{k<=q} exp(s[q,k]-m[k]) * scale[k] * V[k,:]
// Block: 64 q-rows (bh, q0); each wave owns 16 rows. P transits LDS to go
// from C/D layout to A-operand layout (per-wave private buffer, no barrier).
// Writes AttOut[b][s][h*64+d] bf16 for the final output GEMM.
// ---------------------------------------------------------------------------
__global__ __launch_bounds__(256) void attn_pass2(
    const bf16* __restrict__ Qb, const bf16* __restrict__ Kb,
    const bf16* __restrict__ Vt, const float2* __restrict__ stats,
    bf16* __restrict__ AttOut)
{
  const int bh = blockIdx.y;
  const int q0 = blockIdx.x * 64;
  const int tid = threadIdx.x;
  const int w = tid >> 6, lane = tid & 63, lrow = lane & 15, quad = lane >> 4;
  const int qw = q0 + w * 16;
  const bf16* Qh = Qb + (size_t)bh * S * Dh;
  const bf16* Kh = Kb + (size_t)bh * S * Dh;
  const bf16* Vh = Vt + (size_t)bh * Dh * S;   // [d][s]
  const float2* sth = stats + (size_t)bh * S;

  __shared__ bf16 pbuf[4][16][40];

  const bf16* qp = Qh + (size_t)(qw + lrow) * Dh + quad * 8;
  bf16x8 af0 = *(const bf16x8*)(qp);
  bf16x8 af1 = *(const bf16x8*)(qp + 32);

  floatx4 zero = {0.f, 0.f, 0.f, 0.f};
  floatx4 accO[4];
  #pragma unroll
  for (int i = 0; i < 4; ++i) accO[i] = zero;

  for (int kc = 0; kc < qw + 16; kc += 32) {
    const bool full = (kc + 31 <= qw);
    #pragma unroll
    for (int jj = 0; jj < 2; ++jj) {
      const bf16* kp = Kh + (size_t)(kc + jj * 16 + lrow) * Dh + quad * 8;
      bf16x8 kf0 = *(const bf16x8*)(kp);
      bf16x8 kf1 = *(const bf16x8*)(kp + 32);
      floatx4 sacc = zero;
      sacc = MFMA16(af0, kf0, sacc);
      sacc = MFMA16(af1, kf1, sacc);
      int c = kc + jj * 16 + lrow;               // C/D col = lane&15
      float2 st = sth[c];
      #pragma unroll
      for (int r = 0; r < 4; ++r) {
        float p = __expf(sacc[r] - st.x) * st.y; // exp(s-m)/(8*denom)
        if (!full) p = (c <= qw + quad * 4 + r) ? p : 0.f;
        pbuf[w][quad * 4 + r][jj * 16 + lrow] = (bf16)p;
      }
    }
    // A-operand fragment of P: m = lane&15 (q), k = quad*8+j (kpos)
    bf16x8 pf = *(const bf16x8*)&pbuf[w][lrow][quad * 8];
    #pragma unroll
    for (int j2 = 0; j2 < 4; ++j2) {
      bf16x8 vf = *(const bf16x8*)(Vh + (size_t)(j2 * 16 + lrow) * S + kc + quad * 8);
      accO[j2] = MFMA16(pf, vf, accO[j2]);
    }
  }

  const int b = bh >> 4, h = bh & 15;
  #pragma unroll
  for (int j2 = 0; j2 < 4; ++j2) {
    #pragma unroll
    for (int r = 0; r < 4; ++r) {
      int q = qw + quad * 4 + r;
      int d = j2 * 16 + lrow;
      AttOut[((size_t)(b * S + q)) * DM + h * 64 + d] = (bf16)accO[j2][r];
    }
  }
}

// ---------------------------------------------------------------------------
extern "C" void kernel_launch(void* const* d_in, const int* in_sizes, int n_in,
                              void* d_out, int out_size, void* d_ws, size_t ws_size,
                              hipStream_t stream) {
  (void)in_sizes; (void)n_in; (void)out_size; (void)ws_size;
  const float* queries = (const float*)d_in[0];
  const float* keys    = (const float*)d_in[1];
  const float* values  = (const float*)d_in[2];
  const float* Wq_w = (const float*)d_in[3];  const float* Wq_b = (const float*)d_in[4];
  const float* Wk_w = (const float*)d_in[5];  const float* Wk_b = (const float*)d_in[6];
  const float* Wv_w = (const float*)d_in[7];  const float* Wv_b = (const float*)d_in[8];
  const float* Aq_w = (const float*)d_in[9];  const float* Aq_b = (const float*)d_in[10];
  const float* Bq_w = (const float*)d_in[11]; const float* Bq_b = (const float*)d_in[12];
  const float* Ak_w = (const float*)d_in[13]; const float* Ak_b = (const float*)d_in[14];
  const float* Bk_w = (const float*)d_in[15]; const float* Bk_b = (const float*)d_in[16];
  const float* Av_w = (const float*)d_in[17]; const float* Av_b = (const float*)d_in[18];
  const float* Bv_w = (const float*)d_in[19]; const float* Bv_b = (const float*)d_in[20];
  const float* Wo_w = (const float*)d_in[21]; const float* Wo_b = (const float*)d_in[22];
  float* out = (float*)d_out;

  char* ws = (char*)d_ws;
  size_t off = 0;
  auto alloc = [&](size_t bytes) -> void* {
    void* p = ws + off;
    off += (bytes + 255) & ~(size_t)255;
    return p;
  };
  bf16*  X_all  = (bf16*)alloc((size_t)8192 * 3072 * 2);   // [s][q|v|k]
  bf16*  Qb     = (bf16*)alloc((size_t)64 * 2048 * 64 * 2); // [bh][s][d]
  bf16*  Kb     = (bf16*)alloc((size_t)64 * 2048 * 64 * 2); // [bh][s][d]
  bf16*  Vt     = (bf16*)alloc((size_t)64 * 64 * 2048 * 2); // [bh][d][s]
  bf16*  AttOut = (bf16*)alloc((size_t)8192 * 1024 * 2);    // [b*s][h*d]
  bf16*  WqT    = (bf16*)alloc((size_t)1024 * 1024 * 2);
  bf16*  WkT    = (bf16*)alloc((size_t)1024 * 1024 * 2);
  bf16*  WvT    = (bf16*)alloc((size_t)1024 * 2048 * 2);
  bf16*  WoT    = (bf16*)alloc((size_t)1024 * 1024 * 2);
  float* bq     = (float*)alloc(1024 * 4);
  float* bk     = (float*)alloc(1024 * 4);
  float* bv     = (float*)alloc(1024 * 4);
  float* bo     = (float*)alloc(1024 * 4);
  float2* stats = (float2*)alloc((size_t)64 * 2048 * 8);

  prep_convert<<<8192, 256, 0, stream>>>(queries, keys, values, X_all);
  fold_weights<<<dim3(32, 32), dim3(32, 8), 0, stream>>>(
      Wq_w, Aq_w, Bq_w, Wk_w, Ak_w, Bk_w, Wv_w, Av_w, Bv_w, Wo_w,
      WqT, WkT, WvT, WoT);
  fold_bias<<<4, 256, 0, stream>>>(
      Wq_b, Aq_b, Bq_w, Bq_b, Wk_b, Ak_b, Bk_w, Bk_b,
      Wv_b, Av_b, Bv_w, Bv_b, Wo_b, bq, bk, bv, bo);

  // Q = X[:, 0:1024] @ WqT^T ; K = X[:, 2048:3072] @ WkT^T ;
  // V = X[:, 1024:3072] @ WvT^T  (K=2048: [values|keys] vs [Wv_w; Av@Bv])
  gemm_bf16<<<dim3(8, 64), 256, 0, stream>>>(X_all,        3072, WqT, bq, 8192, 1024, 1024, nullptr, Qb, 1);
  gemm_bf16<<<dim3(8, 64), 256, 0, stream>>>(X_all + 2048, 3072, WkT, bk, 8192, 1024, 1024, nullptr, Kb, 1);
  gemm_bf16<<<dim3(8, 64), 256, 0, stream>>>(X_all + 1024, 3072, WvT, bv, 8192, 1024, 2048, nullptr, Vt, 2);

  attn_pass1<<<dim3(32, 64), 256, 0, stream>>>(Qb, Kb, stats);
  attn_pass2<<<dim3(32, 64), 256, 0, stream>>>(Qb, Kb, Vt, stats, AttOut);

  gemm_bf16<<<dim3(8, 64), 256, 0, stream>>>(AttOut, 1024, WoT, bo, 8192, 1024, 1024, out, nullptr, 0);
}

// Round 2
// 592.031 us; speedup vs baseline: 1.5617x; 1.5617x over previous
//
#include <hip/hip_runtime.h>
#include <math.h>

typedef __bf16 bf16;
typedef __bf16 bf16x8 __attribute__((ext_vector_type(8)));
typedef __bf16 bf16x4 __attribute__((ext_vector_type(4)));
typedef float  floatx4 __attribute__((ext_vector_type(4)));

#define MFMA16(a, b, c) __builtin_amdgcn_mfma_f32_16x16x32_bf16(a, b, c, 0, 0, 0)

static constexpr int S  = 2048;
static constexpr int DM = 1024;
static constexpr int Dh = 64;
#define NEGBIG (-1e30f)

// ---------------------------------------------------------------------------
// Pack queries|values|keys into one bf16 [8192][3072] buffer (X_all).
// ---------------------------------------------------------------------------
__global__ __launch_bounds__(256) void prep_convert(
    const float* __restrict__ q, const float* __restrict__ k,
    const float* __restrict__ v, bf16* __restrict__ X)
{
  int s = blockIdx.x;
  int c = threadIdx.x * 4;
  size_t src = (size_t)s * DM + c;
  float4 qv = *(const float4*)(q + src);
  float4 vv = *(const float4*)(v + src);
  float4 kv = *(const float4*)(k + src);
  size_t dst = (size_t)s * (3 * DM);
  bf16x4 t;
  t[0] = (bf16)qv.x; t[1] = (bf16)qv.y; t[2] = (bf16)qv.z; t[3] = (bf16)qv.w;
  *(bf16x4*)(X + dst + c) = t;
  t[0] = (bf16)vv.x; t[1] = (bf16)vv.y; t[2] = (bf16)vv.z; t[3] = (bf16)vv.w;
  *(bf16x4*)(X + dst + DM + c) = t;
  t[0] = (bf16)kv.x; t[1] = (bf16)kv.y; t[2] = (bf16)kv.z; t[3] = (bf16)kv.w;
  *(bf16x4*)(X + dst + 2 * DM + c) = t;
}

// ---------------------------------------------------------------------------
// Fold LoRA into effective weights (transposed bf16 for GEMM B-operand).
// ---------------------------------------------------------------------------
__global__ __launch_bounds__(256) void fold_weights(
    const float* __restrict__ Wq, const float* __restrict__ Aq, const float* __restrict__ Bq,
    const float* __restrict__ Wk, const float* __restrict__ Ak, const float* __restrict__ Bk,
    const float* __restrict__ Wv, const float* __restrict__ Av, const float* __restrict__ Bv,
    const float* __restrict__ Wo,
    bf16* __restrict__ WqT, bf16* __restrict__ WkT,
    bf16* __restrict__ WvT, bf16* __restrict__ WoT)
{
  __shared__ float tile[32][33];
  const int tx = threadIdx.x, ty = threadIdx.y;  // block (32, 8)
  const int n0 = blockIdx.x * 32, k0 = blockIdx.y * 32;
  for (int mi = 0; mi < 5; ++mi) {
    #pragma unroll
    for (int i = 0; i < 4; ++i) {
      int k = k0 + ty + i * 8, n = n0 + tx;
      float val = 0.f;
      if (mi == 0) {
        val = Wq[(size_t)k * DM + n];
        #pragma unroll
        for (int r = 0; r < 8; ++r) val += Aq[k * 8 + r] * Bq[(size_t)r * DM + n];
      } else if (mi == 1) {
        val = Wk[(size_t)k * DM + n];
        #pragma unroll
        for (int r = 0; r < 8; ++r) val += Ak[k * 8 + r] * Bk[(size_t)r * DM + n];
      } else if (mi == 2) {
        val = Wv[(size_t)k * DM + n];
      } else if (mi == 3) {
        #pragma unroll
        for (int r = 0; r < 8; ++r) val += Av[k * 8 + r] * Bv[(size_t)r * DM + n];
      } else {
        val = Wo[(size_t)k * DM + n];
      }
      tile[ty + i * 8][tx] = val;
    }
    __syncthreads();
    #pragma unroll
    for (int i = 0; i < 4; ++i) {
      int n = n0 + ty + i * 8, k = k0 + tx;
      float val = tile[tx][ty + i * 8];
      if (mi == 0)      WqT[(size_t)n * DM + k] = (bf16)val;
      else if (mi == 1) WkT[(size_t)n * DM + k] = (bf16)val;
      else if (mi == 2) WvT[(size_t)n * 2048 + k] = (bf16)val;
      else if (mi == 3) WvT[(size_t)n * 2048 + 1024 + k] = (bf16)val;
      else              WoT[(size_t)n * DM + k] = (bf16)val;
    }
    __syncthreads();
  }
}

__global__ __launch_bounds__(256) void fold_bias(
    const float* __restrict__ Wqb, const float* __restrict__ Aqb,
    const float* __restrict__ BqW, const float* __restrict__ Bqb,
    const float* __restrict__ Wkb, const float* __restrict__ Akb,
    const float* __restrict__ BkW, const float* __restrict__ Bkb,
    const float* __restrict__ Wvb, const float* __restrict__ Avb,
    const float* __restrict__ BvW, const float* __restrict__ Bvb,
    const float* __restrict__ Wob,
    float* __restrict__ bq, float* __restrict__ bk,
    float* __restrict__ bv, float* __restrict__ bo)
{
  int n = blockIdx.x * 256 + threadIdx.x;
  float aq = Wqb[n] + Bqb[n];
  float ak = Wkb[n] + Bkb[n];
  float av = Wvb[n] + Bvb[n];
  #pragma unroll
  for (int r = 0; r < 8; ++r) {
    aq += Aqb[r] * BqW[(size_t)r * DM + n];
    ak += Akb[r] * BkW[(size_t)r * DM + n];
    av += Avb[r] * BvW[(size_t)r * DM + n];
  }
  bq[n] = aq; bk[n] = ak; bv[n] = av; bo[n] = Wob[n];
}

// ---------------------------------------------------------------------------
// 128x128-tile bf16 MFMA GEMM (unchanged this round).
// ---------------------------------------------------------------------------
__global__ __launch_bounds__(256) void gemm_bf16(
    const bf16* __restrict__ A, int lda,
    const bf16* __restrict__ BT,
    const float* __restrict__ bias,
    int M, int N, int K,
    float* __restrict__ outF, bf16* __restrict__ outB, int mode)
{
  __shared__ bf16 sA[128][40];
  __shared__ bf16 sB[128][40];
  const int tid = threadIdx.x;
  const int bm0 = blockIdx.y * 128, bn0 = blockIdx.x * 128;
  const int w = tid >> 6, lane = tid & 63, lrow = lane & 15, quad = lane >> 4;
  const int wm = (w >> 1) * 64, wn = (w & 1) * 64;
  const int r0 = tid >> 2, seg = (tid & 3) * 8;

  const bf16* Ap0 = A + (size_t)(bm0 + r0) * lda + seg;
  const bf16* Ap1 = A + (size_t)(bm0 + r0 + 64) * lda + seg;
  const bf16* Bp0 = BT + (size_t)(bn0 + r0) * K + seg;
  const bf16* Bp1 = BT + (size_t)(bn0 + r0 + 64) * K + seg;

  floatx4 zero = {0.f, 0.f, 0.f, 0.f};
  floatx4 acc[4][4];
  #pragma unroll
  for (int i = 0; i < 4; ++i)
    #pragma unroll
    for (int j = 0; j < 4; ++j) acc[i][j] = zero;

  for (int kt = 0; kt < K; kt += 32) {
    bf16x8 a0 = *(const bf16x8*)(Ap0 + kt);
    bf16x8 a1 = *(const bf16x8*)(Ap1 + kt);
    bf16x8 b0 = *(const bf16x8*)(Bp0 + kt);
    bf16x8 b1 = *(const bf16x8*)(Bp1 + kt);
    __syncthreads();
    *(bf16x8*)&sA[r0][seg] = a0;
    *(bf16x8*)&sA[r0 + 64][seg] = a1;
    *(bf16x8*)&sB[r0][seg] = b0;
    *(bf16x8*)&sB[r0 + 64][seg] = b1;
    __syncthreads();
    bf16x8 aF[4], bF[4];
    #pragma unroll
    for (int i = 0; i < 4; ++i) aF[i] = *(const bf16x8*)&sA[wm + i * 16 + lrow][quad * 8];
    #pragma unroll
    for (int j = 0; j < 4; ++j) bF[j] = *(const bf16x8*)&sB[wn + j * 16 + lrow][quad * 8];
    #pragma unroll
    for (int i = 0; i < 4; ++i)
      #pragma unroll
      for (int j = 0; j < 4; ++j)
        acc[i][j] = MFMA16(aF[i], bF[j], acc[i][j]);
  }

  float bvs[4];
  #pragma unroll
  for (int j = 0; j < 4; ++j) bvs[j] = bias[bn0 + wn + j * 16 + lrow];

  #pragma unroll
  for (int i = 0; i < 4; ++i) {
    #pragma unroll
    for (int j = 0; j < 4; ++j) {
      #pragma unroll
      for (int r = 0; r < 4; ++r) {
        int gm = bm0 + wm + i * 16 + quad * 4 + r;
        int gn = bn0 + wn + j * 16 + lrow;
        float v = acc[i][j][r] + bvs[j];
        if (mode == 0) {
          outF[(size_t)gm * N + gn] = v;
        } else {
          int b = gm >> 11, s = gm & 2047, h = gn >> 6, d = gn & 63;
          size_t idx = (mode == 1)
            ? ((size_t)(b * 16 + h) * 2048 + s) * 64 + d
            : ((size_t)(b * 16 + h) * 64 + d) * 2048 + s;
          outB[idx] = (bf16)v;
        }
      }
    }
  }
}

// ---------------------------------------------------------------------------
// Pass 1: per-column softmax stats (m, 1/(8*sum)) over rows q>=c.
// Block = 128 columns; K frags held in 64 VGPRs; Q streamed with prefetch.
// Branch-free running max via NEGBIG sentinel (contamination self-erases:
// exp(NEGBIG - m_real) == 0 kills any fully-masked-lane garbage on first
// real merge; every column sees its diagonal so a real merge always comes).
// ---------------------------------------------------------------------------
__global__ __launch_bounds__(256, 2) void attn_pass1(
    const bf16* __restrict__ Qb, const bf16* __restrict__ Kb,
    float2* __restrict__ stats)
{
  const int bh = blockIdx.y;
  const int c0 = blockIdx.x * 128;
  const int tid = threadIdx.x;
  const int w = tid >> 6, lane = tid & 63, lrow = lane & 15, quad = lane >> 4;
  const bf16* Qh = Qb + (size_t)bh * S * Dh;
  const bf16* Kh = Kb + (size_t)bh * S * Dh;

  bf16x8 kf[8][2];
  #pragma unroll
  for (int cf = 0; cf < 8; ++cf) {
    const bf16* kp = Kh + (size_t)(c0 + cf * 16 + lrow) * Dh + quad * 8;
    kf[cf][0] = *(const bf16x8*)kp;
    kf[cf][1] = *(const bf16x8*)(kp + 32);
  }

  float rm[8], rs[8];
  #pragma unroll
  for (int cf = 0; cf < 8; ++cf) { rm[cf] = NEGBIG; rs[cf] = 0.f; }

  const int qs = c0 + w * 16;
  const bf16* qp0 = Qh + (size_t)(qs + lrow) * Dh + quad * 8;
  bf16x8 a0 = *(const bf16x8*)qp0, a1 = *(const bf16x8*)(qp0 + 32);

  for (int q0 = qs; q0 < S; q0 += 64) {
    bf16x8 n0 = a0, n1 = a1;
    if (q0 + 64 < S) {
      const bf16* np = Qh + (size_t)(q0 + 64 + lrow) * Dh + quad * 8;
      n0 = *(const bf16x8*)np; n1 = *(const bf16x8*)(np + 32);
    }
    const bool full = (q0 - c0) >= 128;  // all 128 cols <= q0 <= every row
    #pragma unroll
    for (int cf = 0; cf < 8; ++cf) {
      const int c0f = c0 + cf * 16;
      if (!full && c0f > q0 + 15) continue;   // frag fully masked (uniform)
      floatx4 sacc = {0.f, 0.f, 0.f, 0.f};
      sacc = MFMA16(a0, kf[cf][0], sacc);
      sacc = MFMA16(a1, kf[cf][1], sacc);
      float v0 = sacc[0], v1 = sacc[1], v2 = sacc[2], v3 = sacc[3];
      if (!full) {
        int c = c0f + lrow, qb = q0 + quad * 4;
        v0 = (qb + 0 >= c) ? v0 : NEGBIG;
        v1 = (qb + 1 >= c) ? v1 : NEGBIG;
        v2 = (qb + 2 >= c) ? v2 : NEGBIG;
        v3 = (qb + 3 >= c) ? v3 : NEGBIG;
      }
      float mt = fmaxf(fmaxf(v0, v1), fmaxf(v2, v3));
      float nm = fmaxf(rm[cf], mt);
      rs[cf] = rs[cf] * __expf(rm[cf] - nm)
             + __expf(v0 - nm) + __expf(v1 - nm)
             + __expf(v2 - nm) + __expf(v3 - nm);
      rm[cf] = nm;
    }
    a0 = n0; a1 = n1;
  }

  // combine across quads (lanes L, L+16, L+32, L+48 share a column)
  #pragma unroll
  for (int cf = 0; cf < 8; ++cf) {
    #pragma unroll
    for (int off = 16; off < 64; off <<= 1) {
      float om = __shfl_xor(rm[cf], off, 64);
      float os = __shfl_xor(rs[cf], off, 64);
      float nm = fmaxf(rm[cf], om);
      rs[cf] = rs[cf] * __expf(rm[cf] - nm) + os * __expf(om - nm);
      rm[cf] = nm;
    }
  }

  __shared__ float smm[4][128];
  __shared__ float sms[4][128];
  if (quad == 0) {
    #pragma unroll
    for (int cf = 0; cf < 8; ++cf) {
      smm[w][cf * 16 + lrow] = rm[cf];
      sms[w][cf * 16 + lrow] = rs[cf];
    }
  }
  __syncthreads();
  if (tid < 128) {
    float m = smm[0][tid], sum = sms[0][tid];
    #pragma unroll
    for (int ww = 1; ww < 4; ++ww) {
      float om = smm[ww][tid], os = sms[ww][tid];
      float nm = fmaxf(m, om);
      sum = sum * __expf(m - nm) + os * __expf(om - nm);
      m = nm;
    }
    stats[(size_t)bh * S + c0 + tid] = make_float2(m, 1.0f / (8.0f * sum));
  }
}

// ---------------------------------------------------------------------------
// Pass 2: out[q,:] = sum_{k<=q} exp(s[q,k]-m[k]) * scale[k] * V[k,:]
// Block = 128 q-rows; K/V tiles (64 cols x 64 d) staged in LDS once per
// block (shared by all 4 waves); each wave owns 2 m-frags (32 q-rows).
// LDS strides 66/68 elements (odd dword count) -> conflict-free b128 reads.
// ---------------------------------------------------------------------------
__global__ __launch_bounds__(256, 2) void attn_pass2(
    const bf16* __restrict__ Qb, const bf16* __restrict__ Kb,
    const bf16* __restrict__ Vt, const float2* __restrict__ stats,
    bf16* __restrict__ AttOut)
{
  const int bh = blockIdx.y;
  const int q0 = blockIdx.x * 128;
  const int tid = threadIdx.x;
  const int w = tid >> 6, lane = tid & 63, lrow = lane & 15, quad = lane >> 4;
  const bf16* Qh = Qb + (size_t)bh * S * Dh;
  const bf16* Kh = Kb + (size_t)bh * S * Dh;
  const bf16* Vh = Vt + (size_t)bh * Dh * S;   // [d][s]
  const float2* sth = stats + (size_t)bh * S;

  __shared__ bf16 sK[64][66];
  __shared__ bf16 sV[64][66];
  __shared__ bf16 pbuf[4][32][68];

  const int r0m[2] = { q0 + w * 16, q0 + 64 + w * 16 };
  bf16x8 qf[2][2];
  #pragma unroll
  for (int mi = 0; mi < 2; ++mi) {
    const bf16* qp = Qh + (size_t)(r0m[mi] + lrow) * Dh + quad * 8;
    qf[mi][0] = *(const bf16x8*)qp;
    qf[mi][1] = *(const bf16x8*)(qp + 32);
  }

  floatx4 zero = {0.f, 0.f, 0.f, 0.f};
  floatx4 accO[2][4];
  #pragma unroll
  for (int mi = 0; mi < 2; ++mi)
    #pragma unroll
    for (int nf = 0; nf < 4; ++nf) accO[mi][nf] = zero;

  const int sr = tid >> 3;            // 0..31 staging row
  const int sc = (tid & 7) * 8;       // staging col (x8 bf16)
  const int nT = q0 / 64 + 2;         // tiles of 64 columns

  for (int kt = 0; kt < nT; ++kt) {
    const int kc = kt * 64;
    bf16x8 kg0 = *(const bf16x8*)(Kh + (size_t)(kc + sr) * Dh + sc);
    bf16x8 kg1 = *(const bf16x8*)(Kh + (size_t)(kc + sr + 32) * Dh + sc);
    bf16x8 vg0 = *(const bf16x8*)(Vh + (size_t)sr * S + kc + sc);
    bf16x8 vg1 = *(const bf16x8*)(Vh + (size_t)(sr + 32) * S + kc + sc);
    __syncthreads();
    *(bf16x8*)&sK[sr][sc]      = kg0;
    *(bf16x8*)&sK[sr + 32][sc] = kg1;
    *(bf16x8*)&sV[sr][sc]      = vg0;
    *(bf16x8*)&sV[sr + 32][sc] = vg1;
    __syncthreads();

    #pragma unroll
    for (int t = 0; t < 2; ++t) {
      const int cc = kc + t * 32;
      const bool act0 = cc <= r0m[0] + 15;
      const bool act1 = cc <= r0m[1] + 15;
      if (!act0 && !act1) continue;          // wave-uniform; no barriers here

      #pragma unroll
      for (int cf2 = 0; cf2 < 2; ++cf2) {
        const int c0f = cc + cf2 * 16;
        const int cl = t * 32 + cf2 * 16;    // local col base
        bf16x8 kf0 = *(const bf16x8*)&sK[cl + lrow][quad * 8];
        bf16x8 kf1 = *(const bf16x8*)&sK[cl + lrow][quad * 8 + 32];
        const int c = c0f + lrow;
        float2 st = sth[c];
        #pragma unroll
        for (int mi = 0; mi < 2; ++mi) {
          if (!(mi ? act1 : act0)) continue;
          const int r0 = r0m[mi];
          const int prow = mi * 16 + quad * 4;
          if (c0f > r0 + 15) {               // fully masked frag -> zeros
            #pragma unroll
            for (int r = 0; r < 4; ++r)
              pbuf[w][prow + r][cl + lrow] = (bf16)0.f;
          } else {
            floatx4 sacc = zero;
            sacc = MFMA16(qf[mi][0], kf0, sacc);
            sacc = MFMA16(qf[mi][1], kf1, sacc);
            const bool fullf = (c0f + 15 <= r0);
            #pragma unroll
            for (int r = 0; r < 4; ++r) {
              float p = __expf(sacc[r] - st.x) * st.y;
              if (!fullf) p = (c <= r0 + quad * 4 + r) ? p : 0.f;
              pbuf[w][prow + r][cl + lrow] = (bf16)p;
            }
          }
        }
      }

      bf16x8 vf[4];
      #pragma unroll
      for (int nf = 0; nf < 4; ++nf)
        vf[nf] = *(const bf16x8*)&sV[nf * 16 + lrow][t * 32 + quad * 8];
      #pragma unroll
      for (int mi = 0; mi < 2; ++mi) {
        if (!(mi ? act1 : act0)) continue;
        bf16x8 pf = *(const bf16x8*)&pbuf[w][mi * 16 + lrow][t * 32 + quad * 8];
        #pragma unroll
        for (int nf = 0; nf < 4; ++nf)
          accO[mi][nf] = MFMA16(pf, vf[nf], accO[mi][nf]);
      }
    }
  }

  const int b = bh >> 4, h = bh & 15;
  #pragma unroll
  for (int mi = 0; mi < 2; ++mi) {
    #pragma unroll
    for (int nf = 0; nf < 4; ++nf) {
      #pragma unroll
      for (int r = 0; r < 4; ++r) {
        int qq = r0m[mi] + quad * 4 + r;
        int d = nf * 16 + lrow;
        AttOut[((size_t)(b * S + qq)) * DM + h * 64 + d] = (bf16)accO[mi][nf][r];
      }
    }
  }
}

// ---------------------------------------------------------------------------
extern "C" void kernel_launch(void* const* d_in, const int* in_sizes, int n_in,
                              void* d_out, int out_size, void* d_ws, size_t ws_size,
                              hipStream_t stream) {
  (void)in_sizes; (void)n_in; (void)out_size; (void)ws_size;
  const float* queries = (const float*)d_in[0];
  const float* keys    = (const float*)d_in[1];
  const float* values  = (const float*)d_in[2];
  const float* Wq_w = (const float*)d_in[3];  const float* Wq_b = (const float*)d_in[4];
  const float* Wk_w = (const float*)d_in[5];  const float* Wk_b = (const float*)d_in[6];
  const float* Wv_w = (const float*)d_in[7];  const float* Wv_b = (const float*)d_in[8];
  const float* Aq_w = (const float*)d_in[9];  const float* Aq_b = (const float*)d_in[10];
  const float* Bq_w = (const float*)d_in[11]; const float* Bq_b = (const float*)d_in[12];
  const float* Ak_w = (const float*)d_in[13]; const float* Ak_b = (const float*)d_in[14];
  const float* Bk_w = (const float*)d_in[15]; const float* Bk_b = (const float*)d_in[16];
  const float* Av_w = (const float*)d_in[17]; const float* Av_b = (const float*)d_in[18];
  const float* Bv_w = (const float*)d_in[19]; const float* Bv_b = (const float*)d_in[20];
  const float* Wo_w = (const float*)d_in[21]; const float* Wo_b = (const float*)d_in[22];
  float* out = (float*)d_out;

  char* ws = (char*)d_ws;
  size_t off = 0;
  auto alloc = [&](size_t bytes) -> void* {
    void* p = ws + off;
    off += (bytes + 255) & ~(size_t)255;
    return p;
  };
  bf16*  X_all  = (bf16*)alloc((size_t)8192 * 3072 * 2);
  bf16*  Qb     = (bf16*)alloc((size_t)64 * 2048 * 64 * 2);
  bf16*  Kb     = (bf16*)alloc((size_t)64 * 2048 * 64 * 2);
  bf16*  Vt     = (bf16*)alloc((size_t)64 * 64 * 2048 * 2);
  bf16*  AttOut = (bf16*)alloc((size_t)8192 * 1024 * 2);
  bf16*  WqT    = (bf16*)alloc((size_t)1024 * 1024 * 2);
  bf16*  WkT    = (bf16*)alloc((size_t)1024 * 1024 * 2);
  bf16*  WvT    = (bf16*)alloc((size_t)1024 * 2048 * 2);
  bf16*  WoT    = (bf16*)alloc((size_t)1024 * 1024 * 2);
  float* bq     = (float*)alloc(1024 * 4);
  float* bk     = (float*)alloc(1024 * 4);
  float* bv     = (float*)alloc(1024 * 4);
  float* bo     = (float*)alloc(1024 * 4);
  float2* stats = (float2*)alloc((size_t)64 * 2048 * 8);

  prep_convert<<<8192, 256, 0, stream>>>(queries, keys, values, X_all);
  fold_weights<<<dim3(32, 32), dim3(32, 8), 0, stream>>>(
      Wq_w, Aq_w, Bq_w, Wk_w, Ak_w, Bk_w, Wv_w, Av_w, Bv_w, Wo_w,
      WqT, WkT, WvT, WoT);
  fold_bias<<<4, 256, 0, stream>>>(
      Wq_b, Aq_b, Bq_w, Bq_b, Wk_b, Ak_b, Bk_w, Bk_b,
      Wv_b, Av_b, Bv_w, Bv_b, Wo_b, bq, bk, bv, bo);

  gemm_bf16<<<dim3(8, 64), 256, 0, stream>>>(X_all,        3072, WqT, bq, 8192, 1024, 1024, nullptr, Qb, 1);
  gemm_bf16<<<dim3(8, 64), 256, 0, stream>>>(X_all + 2048, 3072, WkT, bk, 8192, 1024, 1024, nullptr, Kb, 1);
  gemm_bf16<<<dim3(8, 64), 256, 0, stream>>>(X_all + 1024, 3072, WvT, bv, 8192, 1024, 2048, nullptr, Vt, 2);

  attn_pass1<<<dim3(16, 64), 256, 0, stream>>>(Qb, Kb, stats);
  attn_pass2<<<dim3(16, 64), 256, 0, stream>>>(Qb, Kb, Vt, stats, AttOut);

  gemm_bf16<<<dim3(8, 64), 256, 0, stream>>>(AttOut, 1024, WoT, bo, 8192, 1024, 1024, out, nullptr, 0);
}

// Round 3
// 549.060 us; speedup vs baseline: 1.6839x; 1.0783x over previous
//
#include <hip/hip_runtime.h>
#include <math.h>
#include <stdint.h>

typedef __bf16 bf16;
typedef __bf16 bf16x8 __attribute__((ext_vector_type(8)));
typedef __bf16 bf16x4 __attribute__((ext_vector_type(4)));
typedef float  floatx4 __attribute__((ext_vector_type(4)));

#define MFMA16(a, b, c) __builtin_amdgcn_mfma_f32_16x16x32_bf16(a, b, c, 0, 0, 0)

static constexpr int S  = 2048;
static constexpr int DM = 1024;
static constexpr int Dh = 64;
#define NEGBIG (-1e30f)

// async global->LDS, 16B per lane; LDS dest = wave-uniform base + lane*16
__device__ __forceinline__ void gload16(const void* g, void* l) {
  __builtin_amdgcn_global_load_lds(
      (const __attribute__((address_space(1))) void*)(uintptr_t)g,
      (__attribute__((address_space(3))) void*)(uintptr_t)l,
      16, 0, 0);
}

// ---------------------------------------------------------------------------
// Pack queries|values|keys into one bf16 [8192][3072] buffer (X_all).
// ---------------------------------------------------------------------------
__global__ __launch_bounds__(256) void prep_convert(
    const float* __restrict__ q, const float* __restrict__ k,
    const float* __restrict__ v, bf16* __restrict__ X)
{
  int s = blockIdx.x;
  int c = threadIdx.x * 4;
  size_t src = (size_t)s * DM + c;
  float4 qv = *(const float4*)(q + src);
  float4 vv = *(const float4*)(v + src);
  float4 kv = *(const float4*)(k + src);
  size_t dst = (size_t)s * (3 * DM);
  bf16x4 t;
  t[0] = (bf16)qv.x; t[1] = (bf16)qv.y; t[2] = (bf16)qv.z; t[3] = (bf16)qv.w;
  *(bf16x4*)(X + dst + c) = t;
  t[0] = (bf16)vv.x; t[1] = (bf16)vv.y; t[2] = (bf16)vv.z; t[3] = (bf16)vv.w;
  *(bf16x4*)(X + dst + DM + c) = t;
  t[0] = (bf16)kv.x; t[1] = (bf16)kv.y; t[2] = (bf16)kv.z; t[3] = (bf16)kv.w;
  *(bf16x4*)(X + dst + 2 * DM + c) = t;
}

// ---------------------------------------------------------------------------
// Fold LoRA into effective weights (transposed bf16 for GEMM B-operand).
// ---------------------------------------------------------------------------
__global__ __launch_bounds__(256) void fold_weights(
    const float* __restrict__ Wq, const float* __restrict__ Aq, const float* __restrict__ Bq,
    const float* __restrict__ Wk, const float* __restrict__ Ak, const float* __restrict__ Bk,
    const float* __restrict__ Wv, const float* __restrict__ Av, const float* __restrict__ Bv,
    const float* __restrict__ Wo,
    bf16* __restrict__ WqT, bf16* __restrict__ WkT,
    bf16* __restrict__ WvT, bf16* __restrict__ WoT)
{
  __shared__ float tile[32][33];
  const int tx = threadIdx.x, ty = threadIdx.y;  // block (32, 8)
  const int n0 = blockIdx.x * 32, k0 = blockIdx.y * 32;
  for (int mi = 0; mi < 5; ++mi) {
    #pragma unroll
    for (int i = 0; i < 4; ++i) {
      int k = k0 + ty + i * 8, n = n0 + tx;
      float val = 0.f;
      if (mi == 0) {
        val = Wq[(size_t)k * DM + n];
        #pragma unroll
        for (int r = 0; r < 8; ++r) val += Aq[k * 8 + r] * Bq[(size_t)r * DM + n];
      } else if (mi == 1) {
        val = Wk[(size_t)k * DM + n];
        #pragma unroll
        for (int r = 0; r < 8; ++r) val += Ak[k * 8 + r] * Bk[(size_t)r * DM + n];
      } else if (mi == 2) {
        val = Wv[(size_t)k * DM + n];
      } else if (mi == 3) {
        #pragma unroll
        for (int r = 0; r < 8; ++r) val += Av[k * 8 + r] * Bv[(size_t)r * DM + n];
      } else {
        val = Wo[(size_t)k * DM + n];
      }
      tile[ty + i * 8][tx] = val;
    }
    __syncthreads();
    #pragma unroll
    for (int i = 0; i < 4; ++i) {
      int n = n0 + ty + i * 8, k = k0 + tx;
      float val = tile[tx][ty + i * 8];
      if (mi == 0)      WqT[(size_t)n * DM + k] = (bf16)val;
      else if (mi == 1) WkT[(size_t)n * DM + k] = (bf16)val;
      else if (mi == 2) WvT[(size_t)n * 2048 + k] = (bf16)val;
      else if (mi == 3) WvT[(size_t)n * 2048 + 1024 + k] = (bf16)val;
      else              WoT[(size_t)n * DM + k] = (bf16)val;
    }
    __syncthreads();
  }
}

__global__ __launch_bounds__(256) void fold_bias(
    const float* __restrict__ Wqb, const float* __restrict__ Aqb,
    const float* __restrict__ BqW, const float* __restrict__ Bqb,
    const float* __restrict__ Wkb, const float* __restrict__ Akb,
    const float* __restrict__ BkW, const float* __restrict__ Bkb,
    const float* __restrict__ Wvb, const float* __restrict__ Avb,
    const float* __restrict__ BvW, const float* __restrict__ Bvb,
    const float* __restrict__ Wob,
    float* __restrict__ bq, float* __restrict__ bk,
    float* __restrict__ bv, float* __restrict__ bo)
{
  int n = blockIdx.x * 256 + threadIdx.x;
  float aq = Wqb[n] + Bqb[n];
  float ak = Wkb[n] + Bkb[n];
  float av = Wvb[n] + Bvb[n];
  #pragma unroll
  for (int r = 0; r < 8; ++r) {
    aq += Aqb[r] * BqW[(size_t)r * DM + n];
    ak += Akb[r] * BkW[(size_t)r * DM + n];
    av += Avb[r] * BvW[(size_t)r * DM + n];
  }
  bq[n] = aq; bk[n] = ak; bv[n] = av; bo[n] = Wob[n];
}

// ---------------------------------------------------------------------------
// m97-style 128x128 bf16 MFMA GEMM: global_load_lds width=16 staging,
// unpadded [128][32] LDS tiles, 2-barrier K-loop.
// mode 0: fp32 [M][N]; mode 1: bf16 [bh][s][d]; mode 2: bf16 [bh][d][s].
// ---------------------------------------------------------------------------
__global__ __launch_bounds__(256) void gemm_bf16(
    const bf16* __restrict__ A, int lda,
    const bf16* __restrict__ BT,
    const float* __restrict__ bias,
    int M, int N, int K,
    float* __restrict__ outF, bf16* __restrict__ outB, int mode)
{
  __shared__ bf16 sA[128 * 32];
  __shared__ bf16 sB[128 * 32];
  const int tid = threadIdx.x;
  const int bm0 = blockIdx.y * 128, bn0 = blockIdx.x * 128;
  const int w = tid >> 6, lane = tid & 63, lrow = lane & 15, quad = lane >> 4;
  const int wm = (w >> 1) * 64, wn = (w & 1) * 64;

  // staging: wave w covers rows [w*32, w*32+32), two 16-row issues each for A,B
  const int srow = lane >> 2;          // 0..15
  const int scol = (lane & 3) * 8;     // bf16 elems (16B granule)
  const bf16* Ag0 = A  + (size_t)(bm0 + w * 32 + srow) * lda + scol;
  const bf16* Ag1 = A  + (size_t)(bm0 + w * 32 + 16 + srow) * lda + scol;
  const bf16* Bg0 = BT + (size_t)(bn0 + w * 32 + srow) * K + scol;
  const bf16* Bg1 = BT + (size_t)(bn0 + w * 32 + 16 + srow) * K + scol;
  bf16* sA0 = &sA[(w * 32) * 32];
  bf16* sA1 = &sA[(w * 32 + 16) * 32];
  bf16* sB0 = &sB[(w * 32) * 32];
  bf16* sB1 = &sB[(w * 32 + 16) * 32];

  floatx4 zero = {0.f, 0.f, 0.f, 0.f};
  floatx4 acc[4][4];
  #pragma unroll
  for (int i = 0; i < 4; ++i)
    #pragma unroll
    for (int j = 0; j < 4; ++j) acc[i][j] = zero;

  for (int kt = 0; kt < K; kt += 32) {
    __syncthreads();                       // prior frag reads done
    gload16(Ag0 + kt, sA0);
    gload16(Ag1 + kt, sA1);
    gload16(Bg0 + kt, sB0);
    gload16(Bg1 + kt, sB1);
    __syncthreads();                       // drains vmcnt -> LDS visible
    bf16x8 aF[4], bF[4];
    #pragma unroll
    for (int i = 0; i < 4; ++i)
      aF[i] = *(const bf16x8*)&sA[(wm + i * 16 + lrow) * 32 + quad * 8];
    #pragma unroll
    for (int j = 0; j < 4; ++j)
      bF[j] = *(const bf16x8*)&sB[(wn + j * 16 + lrow) * 32 + quad * 8];
    #pragma unroll
    for (int i = 0; i < 4; ++i)
      #pragma unroll
      for (int j = 0; j < 4; ++j)
        acc[i][j] = MFMA16(aF[i], bF[j], acc[i][j]);
  }

  float bvs[4];
  #pragma unroll
  for (int j = 0; j < 4; ++j) bvs[j] = bias[bn0 + wn + j * 16 + lrow];

  #pragma unroll
  for (int i = 0; i < 4; ++i) {
    #pragma unroll
    for (int j = 0; j < 4; ++j) {
      #pragma unroll
      for (int r = 0; r < 4; ++r) {
        int gm = bm0 + wm + i * 16 + quad * 4 + r;
        int gn = bn0 + wn + j * 16 + lrow;
        float v = acc[i][j][r] + bvs[j];
        if (mode == 0) {
          outF[(size_t)gm * N + gn] = v;
        } else {
          int b = gm >> 11, s = gm & 2047, h = gn >> 6, d = gn & 63;
          size_t idx = (mode == 1)
            ? ((size_t)(b * 16 + h) * 2048 + s) * 64 + d
            : ((size_t)(b * 16 + h) * 64 + d) * 2048 + s;
          outB[idx] = (bf16)v;
        }
      }
    }
  }
}

// ---------------------------------------------------------------------------
// Pass 1: per-column softmax stats (m, 1/(8*sum)) over rows q>=c.
// Diagonal-paired strips: block x owns cols [x*64,+64) and [(31-x)*64,+64)
// -> constant work per block. K frags in regs; Q streamed with prefetch.
// ---------------------------------------------------------------------------
__global__ __launch_bounds__(256) void attn_pass1(
    const bf16* __restrict__ Qb, const bf16* __restrict__ Kb,
    float2* __restrict__ stats)
{
  const int bh = blockIdx.y;
  const int x = blockIdx.x;              // 0..15
  const int q0a = x * 64, q0b = (31 - x) * 64;
  const int tid = threadIdx.x;
  const int w = tid >> 6, lane = tid & 63, lrow = lane & 15, quad = lane >> 4;
  const bf16* Qh = Qb + (size_t)bh * S * Dh;
  const bf16* Kh = Kb + (size_t)bh * S * Dh;

  int cbase[8];
  #pragma unroll
  for (int cf = 0; cf < 8; ++cf)
    cbase[cf] = (cf < 4) ? (q0a + cf * 16) : (q0b + (cf - 4) * 16);

  bf16x8 kf[8][2];
  #pragma unroll
  for (int cf = 0; cf < 8; ++cf) {
    const bf16* kp = Kh + (size_t)(cbase[cf] + lrow) * Dh + quad * 8;
    kf[cf][0] = *(const bf16x8*)kp;
    kf[cf][1] = *(const bf16x8*)(kp + 32);
  }

  float rm[8], rs[8];
  #pragma unroll
  for (int cf = 0; cf < 8; ++cf) { rm[cf] = NEGBIG; rs[cf] = 0.f; }

  const int qs = q0a + w * 16;
  const bf16* qp0 = Qh + (size_t)(qs + lrow) * Dh + quad * 8;
  bf16x8 a0 = *(const bf16x8*)qp0, a1 = *(const bf16x8*)(qp0 + 32);

  for (int q0 = qs; q0 < S; q0 += 64) {
    bf16x8 n0 = a0, n1 = a1;
    if (q0 + 64 < S) {
      const bf16* np = Qh + (size_t)(q0 + 64 + lrow) * Dh + quad * 8;
      n0 = *(const bf16x8*)np; n1 = *(const bf16x8*)(np + 32);
    }
    #pragma unroll
    for (int cf = 0; cf < 8; ++cf) {
      const int c0f = cbase[cf];
      if (c0f > q0 + 15) continue;          // frag fully masked (uniform)
      floatx4 sacc = {0.f, 0.f, 0.f, 0.f};
      sacc = MFMA16(a0, kf[cf][0], sacc);
      sacc = MFMA16(a1, kf[cf][1], sacc);
      float v0 = sacc[0], v1 = sacc[1], v2 = sacc[2], v3 = sacc[3];
      if (q0 < c0f + 15) {                  // partially masked frag
        int c = c0f + lrow, qb = q0 + quad * 4;
        v0 = (qb + 0 >= c) ? v0 : NEGBIG;
        v1 = (qb + 1 >= c) ? v1 : NEGBIG;
        v2 = (qb + 2 >= c) ? v2 : NEGBIG;
        v3 = (qb + 3 >= c) ? v3 : NEGBIG;
      }
      float mt = fmaxf(fmaxf(v0, v1), fmaxf(v2, v3));
      float nm = fmaxf(rm[cf], mt);
      rs[cf] = rs[cf] * __expf(rm[cf] - nm)
             + __expf(v0 - nm) + __expf(v1 - nm)
             + __expf(v2 - nm) + __expf(v3 - nm);
      rm[cf] = nm;
    }
    a0 = n0; a1 = n1;
  }

  #pragma unroll
  for (int cf = 0; cf < 8; ++cf) {
    #pragma unroll
    for (int off = 16; off < 64; off <<= 1) {
      float om = __shfl_xor(rm[cf], off, 64);
      float os = __shfl_xor(rs[cf], off, 64);
      float nm = fmaxf(rm[cf], om);
      rs[cf] = rs[cf] * __expf(rm[cf] - nm) + os * __expf(om - nm);
      rm[cf] = nm;
    }
  }

  __shared__ float smm[4][128];
  __shared__ float sms[4][128];
  if (quad == 0) {
    #pragma unroll
    for (int cf = 0; cf < 8; ++cf) {
      smm[w][cf * 16 + lrow] = rm[cf];
      sms[w][cf * 16 + lrow] = rs[cf];
    }
  }
  __syncthreads();
  if (tid < 128) {
    float m = smm[0][tid], sum = sms[0][tid];
    #pragma unroll
    for (int ww = 1; ww < 4; ++ww) {
      float om = smm[ww][tid], os = sms[ww][tid];
      float nm = fmaxf(m, om);
      sum = sum * __expf(m - nm) + os * __expf(om - nm);
      m = nm;
    }
    int col = (tid < 64) ? (q0a + tid) : (q0b + tid - 64);
    stats[(size_t)bh * S + col] = make_float2(m, 1.0f / (8.0f * sum));
  }
}

// ---------------------------------------------------------------------------
// Pass 2: out[q,:] = sum_{k<=q} exp(s[q,k]-m[k]) * scale[k] * V[k,:]
// Diagonal-paired strips (x*64 and (31-x)*64) -> constant compute per block.
// K/V staged in granule-major LDS (all vector accesses 16B-aligned, bank
// usage at floor). Reg-prefetch of next tile overlaps compute.
// ---------------------------------------------------------------------------
__global__ __launch_bounds__(256) void attn_pass2(
    const bf16* __restrict__ Qb, const bf16* __restrict__ Kb,
    const bf16* __restrict__ Vt, const float2* __restrict__ stats,
    bf16* __restrict__ AttOut)
{
  const int bh = blockIdx.y;
  const int x = blockIdx.x;              // 0..15
  const int q0a = x * 64, q0b = (31 - x) * 64;
  const int tid = threadIdx.x;
  const int w = tid >> 6, lane = tid & 63, lrow = lane & 15, quad = lane >> 4;
  const bf16* Qh = Qb + (size_t)bh * S * Dh;
  const bf16* Kh = Kb + (size_t)bh * S * Dh;
  const bf16* Vh = Vt + (size_t)bh * Dh * S;   // [d][s]
  const float2* sth = stats + (size_t)bh * S;

  __shared__ bf16 sK2[8][64][8];   // [d-granule][s-row][8]  (16B rows)
  __shared__ bf16 sV2[8][64][8];   // [s-granule][d-row][8]
  __shared__ bf16 pbuf[4][32][40]; // 80B rows: 16B-aligned b128 frag reads

  const int r0m[2] = { q0a + w * 16, q0b + w * 16 };
  bf16x8 qf[2][2];
  #pragma unroll
  for (int mi = 0; mi < 2; ++mi) {
    const bf16* qp = Qh + (size_t)(r0m[mi] + lrow) * Dh + quad * 8;
    qf[mi][0] = *(const bf16x8*)qp;
    qf[mi][1] = *(const bf16x8*)(qp + 32);
  }

  floatx4 zero = {0.f, 0.f, 0.f, 0.f};
  floatx4 accO[2][4];
  #pragma unroll
  for (int mi = 0; mi < 2; ++mi)
    #pragma unroll
    for (int nf = 0; nf < 4; ++nf) accO[mi][nf] = zero;

  const int sr = tid >> 3;        // 0..31
  const int g  = tid & 7;         // 16B granule
  const int nT = 32 - x;          // tiles of 64 cols (covers strip B fully)

  // prefetch tile 0
  bf16x8 kg0 = *(const bf16x8*)(Kh + (size_t)sr * Dh + g * 8);
  bf16x8 kg1 = *(const bf16x8*)(Kh + (size_t)(sr + 32) * Dh + g * 8);
  bf16x8 vg0 = *(const bf16x8*)(Vh + (size_t)sr * S + g * 8);
  bf16x8 vg1 = *(const bf16x8*)(Vh + (size_t)(sr + 32) * S + g * 8);

  for (int kt = 0; kt < nT; ++kt) {
    const int kc = kt * 64;
    __syncthreads();
    *(bf16x8*)&sK2[g][sr][0]      = kg0;
    *(bf16x8*)&sK2[g][sr + 32][0] = kg1;
    *(bf16x8*)&sV2[g][sr][0]      = vg0;
    *(bf16x8*)&sV2[g][sr + 32][0] = vg1;
    __syncthreads();
    if (kt + 1 < nT) {                     // prefetch next tile into regs
      const int kn = kc + 64;
      kg0 = *(const bf16x8*)(Kh + (size_t)(kn + sr) * Dh + g * 8);
      kg1 = *(const bf16x8*)(Kh + (size_t)(kn + sr + 32) * Dh + g * 8);
      vg0 = *(const bf16x8*)(Vh + (size_t)sr * S + kn + g * 8);
      vg1 = *(const bf16x8*)(Vh + (size_t)(sr + 32) * S + kn + g * 8);
    }

    #pragma unroll
    for (int t = 0; t < 2; ++t) {
      const int cc = kc + t * 32;
      const bool act0 = cc <= r0m[0] + 15;
      const bool act1 = cc <= r0m[1] + 15;
      if (!act0 && !act1) continue;        // wave-uniform; no barriers below

      #pragma unroll
      for (int cf2 = 0; cf2 < 2; ++cf2) {
        const int c0f = cc + cf2 * 16;
        const int cl = t * 32 + cf2 * 16;  // tile-local s row base
        bf16x8 kf0 = *(const bf16x8*)&sK2[quad][cl + lrow][0];
        bf16x8 kf1 = *(const bf16x8*)&sK2[4 + quad][cl + lrow][0];
        const int c = c0f + lrow;
        float2 st = sth[c];
        #pragma unroll
        for (int mi = 0; mi < 2; ++mi) {
          if (!(mi ? act1 : act0)) continue;
          const int r0 = r0m[mi];
          const int prow = mi * 16 + quad * 4;
          if (c0f > r0 + 15) {             // fully masked frag -> zeros
            #pragma unroll
            for (int r = 0; r < 4; ++r)
              pbuf[w][prow + r][cf2 * 16 + lrow] = (bf16)0.f;
          } else {
            floatx4 sacc = zero;
            sacc = MFMA16(qf[mi][0], kf0, sacc);
            sacc = MFMA16(qf[mi][1], kf1, sacc);
            const bool fullf = (c0f + 15 <= r0);
            #pragma unroll
            for (int r = 0; r < 4; ++r) {
              float p = __expf(sacc[r] - st.x) * st.y;
              if (!fullf) p = (c <= r0 + quad * 4 + r) ? p : 0.f;
              pbuf[w][prow + r][cf2 * 16 + lrow] = (bf16)p;
            }
          }
        }
      }

      bf16x8 vf[4];
      #pragma unroll
      for (int nf = 0; nf < 4; ++nf)
        vf[nf] = *(const bf16x8*)&sV2[t * 4 + quad][nf * 16 + lrow][0];
      #pragma unroll
      for (int mi = 0; mi < 2; ++mi) {
        if (!(mi ? act1 : act0)) continue;
        bf16x8 pf = *(const bf16x8*)&pbuf[w][mi * 16 + lrow][quad * 8];
        #pragma unroll
        for (int nf = 0; nf < 4; ++nf)
          accO[mi][nf] = MFMA16(pf, vf[nf], accO[mi][nf]);
      }
    }
  }

  const int b = bh >> 4, h = bh & 15;
  #pragma unroll
  for (int mi = 0; mi < 2; ++mi) {
    #pragma unroll
    for (int nf = 0; nf < 4; ++nf) {
      #pragma unroll
      for (int r = 0; r < 4; ++r) {
        int qq = r0m[mi] + quad * 4 + r;
        int d = nf * 16 + lrow;
        AttOut[((size_t)(b * S + qq)) * DM + h * 64 + d] = (bf16)accO[mi][nf][r];
      }
    }
  }
}

// ---------------------------------------------------------------------------
extern "C" void kernel_launch(void* const* d_in, const int* in_sizes, int n_in,
                              void* d_out, int out_size, void* d_ws, size_t ws_size,
                              hipStream_t stream) {
  (void)in_sizes; (void)n_in; (void)out_size; (void)ws_size;
  const float* queries = (const float*)d_in[0];
  const float* keys    = (const float*)d_in[1];
  const float* values  = (const float*)d_in[2];
  const float* Wq_w = (const float*)d_in[3];  const float* Wq_b = (const float*)d_in[4];
  const float* Wk_w = (const float*)d_in[5];  const float* Wk_b = (const float*)d_in[6];
  const float* Wv_w = (const float*)d_in[7];  const float* Wv_b = (const float*)d_in[8];
  const float* Aq_w = (const float*)d_in[9];  const float* Aq_b = (const float*)d_in[10];
  const float* Bq_w = (const float*)d_in[11]; const float* Bq_b = (const float*)d_in[12];
  const float* Ak_w = (const float*)d_in[13]; const float* Ak_b = (const float*)d_in[14];
  const float* Bk_w = (const float*)d_in[15]; const float* Bk_b = (const float*)d_in[16];
  const float* Av_w = (const float*)d_in[17]; const float* Av_b = (const float*)d_in[18];
  const float* Bv_w = (const float*)d_in[19]; const float* Bv_b = (const float*)d_in[20];
  const float* Wo_w = (const float*)d_in[21]; const float* Wo_b = (const float*)d_in[22];
  float* out = (float*)d_out;

  char* ws = (char*)d_ws;
  size_t off = 0;
  auto alloc = [&](size_t bytes) -> void* {
    void* p = ws + off;
    off += (bytes + 255) & ~(size_t)255;
    return p;
  };
  bf16*  X_all  = (bf16*)alloc((size_t)8192 * 3072 * 2);
  bf16*  Qb     = (bf16*)alloc((size_t)64 * 2048 * 64 * 2);
  bf16*  Kb     = (bf16*)alloc((size_t)64 * 2048 * 64 * 2);
  bf16*  Vt     = (bf16*)alloc((size_t)64 * 64 * 2048 * 2);
  bf16*  AttOut = (bf16*)alloc((size_t)8192 * 1024 * 2);
  bf16*  WqT    = (bf16*)alloc((size_t)1024 * 1024 * 2);
  bf16*  WkT    = (bf16*)alloc((size_t)1024 * 1024 * 2);
  bf16*  WvT    = (bf16*)alloc((size_t)1024 * 2048 * 2);
  bf16*  WoT    = (bf16*)alloc((size_t)1024 * 1024 * 2);
  float* bq     = (float*)alloc(1024 * 4);
  float* bk     = (float*)alloc(1024 * 4);
  float* bv     = (float*)alloc(1024 * 4);
  float* bo     = (float*)alloc(1024 * 4);
  float2* stats = (float2*)alloc((size_t)64 * 2048 * 8);

  prep_convert<<<8192, 256, 0, stream>>>(queries, keys, values, X_all);
  fold_weights<<<dim3(32, 32), dim3(32, 8), 0, stream>>>(
      Wq_w, Aq_w, Bq_w, Wk_w, Ak_w, Bk_w, Wv_w, Av_w, Bv_w, Wo_w,
      WqT, WkT, WvT, WoT);
  fold_bias<<<4, 256, 0, stream>>>(
      Wq_b, Aq_b, Bq_w, Bq_b, Wk_b, Ak_b, Bk_w, Bk_b,
      Wv_b, Av_b, Bv_w, Bv_b, Wo_b, bq, bk, bv, bo);

  gemm_bf16<<<dim3(8, 64), 256, 0, stream>>>(X_all,        3072, WqT, bq, 8192, 1024, 1024, nullptr, Qb, 1);
  gemm_bf16<<<dim3(8, 64), 256, 0, stream>>>(X_all + 2048, 3072, WkT, bk, 8192, 1024, 1024, nullptr, Kb, 1);
  gemm_bf16<<<dim3(8, 64), 256, 0, stream>>>(X_all + 1024, 3072, WvT, bv, 8192, 1024, 2048, nullptr, Vt, 2);

  attn_pass1<<<dim3(16, 64), 256, 0, stream>>>(Qb, Kb, stats);
  attn_pass2<<<dim3(16, 64), 256, 0, stream>>>(Qb, Kb, Vt, stats, AttOut);

  gemm_bf16<<<dim3(8, 64), 256, 0, stream>>>(AttOut, 1024, WoT, bo, 8192, 1024, 1024, out, nullptr, 0);
}

// Round 4
// 530.001 us; speedup vs baseline: 1.7445x; 1.0360x over previous
//
#include <hip/hip_runtime.h>
#include <math.h>
#include <stdint.h>

typedef __bf16 bf16;
typedef __bf16 bf16x8 __attribute__((ext_vector_type(8)));
typedef __bf16 bf16x4 __attribute__((ext_vector_type(4)));
typedef float  floatx4 __attribute__((ext_vector_type(4)));

#define MFMA16(a, b, c) __builtin_amdgcn_mfma_f32_16x16x32_bf16(a, b, c, 0, 0, 0)

static constexpr int S  = 2048;
static constexpr int DM = 1024;
static constexpr int Dh = 64;
#define NEGBIG (-1e30f)
#define LOG2E  1.44269504088896340736f

// async global->LDS, 16B per lane; LDS dest = wave-uniform base + lane*16
__device__ __forceinline__ void gload16(const void* g, void* l) {
  __builtin_amdgcn_global_load_lds(
      (const __attribute__((address_space(1))) void*)(uintptr_t)g,
      (__attribute__((address_space(3))) void*)(uintptr_t)l,
      16, 0, 0);
}

// ---------------------------------------------------------------------------
// Pack queries|values|keys into one bf16 [8192][3072] buffer (X_all).
// ---------------------------------------------------------------------------
__global__ __launch_bounds__(256) void prep_convert(
    const float* __restrict__ q, const float* __restrict__ k,
    const float* __restrict__ v, bf16* __restrict__ X)
{
  int s = blockIdx.x;
  int c = threadIdx.x * 4;
  size_t src = (size_t)s * DM + c;
  float4 qv = *(const float4*)(q + src);
  float4 vv = *(const float4*)(v + src);
  float4 kv = *(const float4*)(k + src);
  size_t dst = (size_t)s * (3 * DM);
  bf16x4 t;
  t[0] = (bf16)qv.x; t[1] = (bf16)qv.y; t[2] = (bf16)qv.z; t[3] = (bf16)qv.w;
  *(bf16x4*)(X + dst + c) = t;
  t[0] = (bf16)vv.x; t[1] = (bf16)vv.y; t[2] = (bf16)vv.z; t[3] = (bf16)vv.w;
  *(bf16x4*)(X + dst + DM + c) = t;
  t[0] = (bf16)kv.x; t[1] = (bf16)kv.y; t[2] = (bf16)kv.z; t[3] = (bf16)kv.w;
  *(bf16x4*)(X + dst + 2 * DM + c) = t;
}

// ---------------------------------------------------------------------------
// Fold LoRA into effective weights (transposed bf16 for GEMM B-operand).
// ---------------------------------------------------------------------------
__global__ __launch_bounds__(256) void fold_weights(
    const float* __restrict__ Wq, const float* __restrict__ Aq, const float* __restrict__ Bq,
    const float* __restrict__ Wk, const float* __restrict__ Ak, const float* __restrict__ Bk,
    const float* __restrict__ Wv, const float* __restrict__ Av, const float* __restrict__ Bv,
    const float* __restrict__ Wo,
    bf16* __restrict__ WqT, bf16* __restrict__ WkT,
    bf16* __restrict__ WvT, bf16* __restrict__ WoT)
{
  __shared__ float tile[32][33];
  const int tx = threadIdx.x, ty = threadIdx.y;  // block (32, 8)
  const int n0 = blockIdx.x * 32, k0 = blockIdx.y * 32;
  for (int mi = 0; mi < 5; ++mi) {
    #pragma unroll
    for (int i = 0; i < 4; ++i) {
      int k = k0 + ty + i * 8, n = n0 + tx;
      float val = 0.f;
      if (mi == 0) {
        val = Wq[(size_t)k * DM + n];
        #pragma unroll
        for (int r = 0; r < 8; ++r) val += Aq[k * 8 + r] * Bq[(size_t)r * DM + n];
      } else if (mi == 1) {
        val = Wk[(size_t)k * DM + n];
        #pragma unroll
        for (int r = 0; r < 8; ++r) val += Ak[k * 8 + r] * Bk[(size_t)r * DM + n];
      } else if (mi == 2) {
        val = Wv[(size_t)k * DM + n];
      } else if (mi == 3) {
        #pragma unroll
        for (int r = 0; r < 8; ++r) val += Av[k * 8 + r] * Bv[(size_t)r * DM + n];
      } else {
        val = Wo[(size_t)k * DM + n];
      }
      tile[ty + i * 8][tx] = val;
    }
    __syncthreads();
    #pragma unroll
    for (int i = 0; i < 4; ++i) {
      int n = n0 + ty + i * 8, k = k0 + tx;
      float val = tile[tx][ty + i * 8];
      if (mi == 0)      WqT[(size_t)n * DM + k] = (bf16)val;
      else if (mi == 1) WkT[(size_t)n * DM + k] = (bf16)val;
      else if (mi == 2) WvT[(size_t)n * 2048 + k] = (bf16)val;
      else if (mi == 3) WvT[(size_t)n * 2048 + 1024 + k] = (bf16)val;
      else              WoT[(size_t)n * DM + k] = (bf16)val;
    }
    __syncthreads();
  }
}

__global__ __launch_bounds__(256) void fold_bias(
    const float* __restrict__ Wqb, const float* __restrict__ Aqb,
    const float* __restrict__ BqW, const float* __restrict__ Bqb,
    const float* __restrict__ Wkb, const float* __restrict__ Akb,
    const float* __restrict__ BkW, const float* __restrict__ Bkb,
    const float* __restrict__ Wvb, const float* __restrict__ Avb,
    const float* __restrict__ BvW, const float* __restrict__ Bvb,
    const float* __restrict__ Wob,
    float* __restrict__ bq, float* __restrict__ bk,
    float* __restrict__ bv, float* __restrict__ bo)
{
  int n = blockIdx.x * 256 + threadIdx.x;
  float aq = Wqb[n] + Bqb[n];
  float ak = Wkb[n] + Bkb[n];
  float av = Wvb[n] + Bvb[n];
  #pragma unroll
  for (int r = 0; r < 8; ++r) {
    aq += Aqb[r] * BqW[(size_t)r * DM + n];
    ak += Akb[r] * BkW[(size_t)r * DM + n];
    av += Avb[r] * BvW[(size_t)r * DM + n];
  }
  bq[n] = aq; bk[n] = ak; bv[n] = av; bo[n] = Wob[n];
}

// ---------------------------------------------------------------------------
// m97-style 128x128 bf16 MFMA GEMM: global_load_lds width=16 staging,
// unpadded [128][32] LDS tiles, 2-barrier K-loop.
// mode 0: fp32 [M][N]; mode 1: bf16 [bh][s][d]; mode 2: bf16 [bh][d][s].
// oscale multiplies (acc+bias) before store (folds log2e into Q).
// ---------------------------------------------------------------------------
__global__ __launch_bounds__(256) void gemm_bf16(
    const bf16* __restrict__ A, int lda,
    const bf16* __restrict__ BT,
    const float* __restrict__ bias,
    int M, int N, int K, float oscale,
    float* __restrict__ outF, bf16* __restrict__ outB, int mode)
{
  __shared__ bf16 sA[128 * 32];
  __shared__ bf16 sB[128 * 32];
  const int tid = threadIdx.x;
  const int bm0 = blockIdx.y * 128, bn0 = blockIdx.x * 128;
  const int w = tid >> 6, lane = tid & 63, lrow = lane & 15, quad = lane >> 4;
  const int wm = (w >> 1) * 64, wn = (w & 1) * 64;

  const int srow = lane >> 2;          // 0..15
  const int scol = (lane & 3) * 8;     // bf16 elems (16B granule)
  const bf16* Ag0 = A  + (size_t)(bm0 + w * 32 + srow) * lda + scol;
  const bf16* Ag1 = A  + (size_t)(bm0 + w * 32 + 16 + srow) * lda + scol;
  const bf16* Bg0 = BT + (size_t)(bn0 + w * 32 + srow) * K + scol;
  const bf16* Bg1 = BT + (size_t)(bn0 + w * 32 + 16 + srow) * K + scol;
  bf16* sA0 = &sA[(w * 32) * 32];
  bf16* sA1 = &sA[(w * 32 + 16) * 32];
  bf16* sB0 = &sB[(w * 32) * 32];
  bf16* sB1 = &sB[(w * 32 + 16) * 32];

  floatx4 zero = {0.f, 0.f, 0.f, 0.f};
  floatx4 acc[4][4];
  #pragma unroll
  for (int i = 0; i < 4; ++i)
    #pragma unroll
    for (int j = 0; j < 4; ++j) acc[i][j] = zero;

  for (int kt = 0; kt < K; kt += 32) {
    __syncthreads();
    gload16(Ag0 + kt, sA0);
    gload16(Ag1 + kt, sA1);
    gload16(Bg0 + kt, sB0);
    gload16(Bg1 + kt, sB1);
    __syncthreads();
    bf16x8 aF[4], bF[4];
    #pragma unroll
    for (int i = 0; i < 4; ++i)
      aF[i] = *(const bf16x8*)&sA[(wm + i * 16 + lrow) * 32 + quad * 8];
    #pragma unroll
    for (int j = 0; j < 4; ++j)
      bF[j] = *(const bf16x8*)&sB[(wn + j * 16 + lrow) * 32 + quad * 8];
    #pragma unroll
    for (int i = 0; i < 4; ++i)
      #pragma unroll
      for (int j = 0; j < 4; ++j)
        acc[i][j] = MFMA16(aF[i], bF[j], acc[i][j]);
  }

  float bvs[4];
  #pragma unroll
  for (int j = 0; j < 4; ++j) bvs[j] = bias[bn0 + wn + j * 16 + lrow];

  #pragma unroll
  for (int i = 0; i < 4; ++i) {
    #pragma unroll
    for (int j = 0; j < 4; ++j) {
      #pragma unroll
      for (int r = 0; r < 4; ++r) {
        int gm = bm0 + wm + i * 16 + quad * 4 + r;
        int gn = bn0 + wn + j * 16 + lrow;
        float v = (acc[i][j][r] + bvs[j]) * oscale;
        if (mode == 0) {
          outF[(size_t)gm * N + gn] = v;
        } else {
          int b = gm >> 11, s = gm & 2047, h = gn >> 6, d = gn & 63;
          size_t idx = (mode == 1)
            ? ((size_t)(b * 16 + h) * 2048 + s) * 64 + d
            : ((size_t)(b * 16 + h) * 64 + d) * 2048 + s;
          outB[idx] = (bf16)v;
        }
      }
    }
  }
}

// ---------------------------------------------------------------------------
// Pass 1 (log2 domain; Q pre-scaled by log2e): per-column stats over q>=c.
// Emits single constant C[c] = m + 3 + log2(sum) so pass2's weight is
// exp2(s - C) = exp(s_e - m_e) / (8*sum)  -- sub+exp2 only per element.
// Diagonal-paired strips -> constant work per block.
// ---------------------------------------------------------------------------
__global__ __launch_bounds__(256) void attn_pass1(
    const bf16* __restrict__ Qb, const bf16* __restrict__ Kb,
    float* __restrict__ statC)
{
  const int bh = blockIdx.y;
  const int x = blockIdx.x;              // 0..15
  const int q0a = x * 64, q0b = (31 - x) * 64;
  const int tid = threadIdx.x;
  const int w = tid >> 6, lane = tid & 63, lrow = lane & 15, quad = lane >> 4;
  const bf16* Qh = Qb + (size_t)bh * S * Dh;
  const bf16* Kh = Kb + (size_t)bh * S * Dh;

  int cbase[8];
  #pragma unroll
  for (int cf = 0; cf < 8; ++cf)
    cbase[cf] = (cf < 4) ? (q0a + cf * 16) : (q0b + (cf - 4) * 16);

  bf16x8 kf[8][2];
  #pragma unroll
  for (int cf = 0; cf < 8; ++cf) {
    const bf16* kp = Kh + (size_t)(cbase[cf] + lrow) * Dh + quad * 8;
    kf[cf][0] = *(const bf16x8*)kp;
    kf[cf][1] = *(const bf16x8*)(kp + 32);
  }

  float rm[8], rs[8];
  #pragma unroll
  for (int cf = 0; cf < 8; ++cf) { rm[cf] = NEGBIG; rs[cf] = 0.f; }

  const int qs = q0a + w * 16;
  const bf16* qp0 = Qh + (size_t)(qs + lrow) * Dh + quad * 8;
  bf16x8 a0 = *(const bf16x8*)qp0, a1 = *(const bf16x8*)(qp0 + 32);

  for (int q0 = qs; q0 < S; q0 += 64) {
    bf16x8 n0 = a0, n1 = a1;
    if (q0 + 64 < S) {
      const bf16* np = Qh + (size_t)(q0 + 64 + lrow) * Dh + quad * 8;
      n0 = *(const bf16x8*)np; n1 = *(const bf16x8*)(np + 32);
    }
    #pragma unroll
    for (int cf = 0; cf < 8; ++cf) {
      const int c0f = cbase[cf];
      if (c0f > q0 + 15) continue;          // frag fully masked (uniform)
      floatx4 sacc = {0.f, 0.f, 0.f, 0.f};
      sacc = MFMA16(a0, kf[cf][0], sacc);
      sacc = MFMA16(a1, kf[cf][1], sacc);
      float v0 = sacc[0], v1 = sacc[1], v2 = sacc[2], v3 = sacc[3];
      if (q0 < c0f + 15) {                  // partially masked frag
        int c = c0f + lrow, qb = q0 + quad * 4;
        v0 = (qb + 0 >= c) ? v0 : NEGBIG;
        v1 = (qb + 1 >= c) ? v1 : NEGBIG;
        v2 = (qb + 2 >= c) ? v2 : NEGBIG;
        v3 = (qb + 3 >= c) ? v3 : NEGBIG;
      }
      float mt = fmaxf(fmaxf(v0, v1), fmaxf(v2, v3));
      float nm = fmaxf(rm[cf], mt);
      rs[cf] = rs[cf] * exp2f(rm[cf] - nm)
             + exp2f(v0 - nm) + exp2f(v1 - nm)
             + exp2f(v2 - nm) + exp2f(v3 - nm);
      rm[cf] = nm;
    }
    a0 = n0; a1 = n1;
  }

  #pragma unroll
  for (int cf = 0; cf < 8; ++cf) {
    #pragma unroll
    for (int off = 16; off < 64; off <<= 1) {
      float om = __shfl_xor(rm[cf], off, 64);
      float os = __shfl_xor(rs[cf], off, 64);
      float nm = fmaxf(rm[cf], om);
      rs[cf] = rs[cf] * exp2f(rm[cf] - nm) + os * exp2f(om - nm);
      rm[cf] = nm;
    }
  }

  __shared__ float smm[4][128];
  __shared__ float sms[4][128];
  if (quad == 0) {
    #pragma unroll
    for (int cf = 0; cf < 8; ++cf) {
      smm[w][cf * 16 + lrow] = rm[cf];
      sms[w][cf * 16 + lrow] = rs[cf];
    }
  }
  __syncthreads();
  if (tid < 128) {
    float m = smm[0][tid], sum = sms[0][tid];
    #pragma unroll
    for (int ww = 1; ww < 4; ++ww) {
      float om = smm[ww][tid], os = sms[ww][tid];
      float nm = fmaxf(m, om);
      sum = sum * exp2f(m - nm) + os * exp2f(om - nm);
      m = nm;
    }
    int col = (tid < 64) ? (q0a + tid) : (q0b + tid - 64);
    statC[(size_t)bh * S + col] = m + 3.0f + __log2f(sum);
  }
}

// ---------------------------------------------------------------------------
// Pass 2: out[q,:] = sum_{k<=q} exp2(s[q,k] - C[k]) * V[k,:]
// Diagonal-paired strips. K/V in granule-major LDS with 144B rows (9
// granules: row stride not 0 mod 128B -> staging writes AND frag reads hit
// all 32 banks at the phase floor). pbuf per-wave [32][5][8] (80B rows),
// double-buffered across 32-col steps to break the WAR serialization.
// ---------------------------------------------------------------------------
__global__ __launch_bounds__(256) void attn_pass2(
    const bf16* __restrict__ Qb, const bf16* __restrict__ Kb,
    const bf16* __restrict__ Vt, const float* __restrict__ statC,
    bf16* __restrict__ AttOut)
{
  const int bh = blockIdx.y;
  const int x = blockIdx.x;              // 0..15
  const int q0a = x * 64, q0b = (31 - x) * 64;
  const int tid = threadIdx.x;
  const int w = tid >> 6, lane = tid & 63, lrow = lane & 15, quad = lane >> 4;
  const bf16* Qh = Qb + (size_t)bh * S * Dh;
  const bf16* Kh = Kb + (size_t)bh * S * Dh;
  const bf16* Vh = Vt + (size_t)bh * Dh * S;   // [d][s]
  const float* sth = statC + (size_t)bh * S;

  __shared__ bf16 sK[64][9][8];        // [s-row][d-granule(+pad)][8]
  __shared__ bf16 sV[64][9][8];        // [d-row][s-granule(+pad)][8]
  __shared__ bf16 pbuf[2][4][32][5][8];// [dbuf][wave][q-row][k-granule(+pad)][8]

  const int r0m[2] = { q0a + w * 16, q0b + w * 16 };
  bf16x8 qf[2][2];
  #pragma unroll
  for (int mi = 0; mi < 2; ++mi) {
    const bf16* qp = Qh + (size_t)(r0m[mi] + lrow) * Dh + quad * 8;
    qf[mi][0] = *(const bf16x8*)qp;
    qf[mi][1] = *(const bf16x8*)(qp + 32);
  }

  floatx4 zero = {0.f, 0.f, 0.f, 0.f};
  floatx4 accO[2][4];
  #pragma unroll
  for (int mi = 0; mi < 2; ++mi)
    #pragma unroll
    for (int nf = 0; nf < 4; ++nf) accO[mi][nf] = zero;

  const int sr = tid >> 3;        // 0..31
  const int g  = tid & 7;         // 16B granule
  const int nT = 32 - x;          // tiles of 64 cols

  // prefetch tile 0
  bf16x8 kg0 = *(const bf16x8*)(Kh + (size_t)sr * Dh + g * 8);
  bf16x8 kg1 = *(const bf16x8*)(Kh + (size_t)(sr + 32) * Dh + g * 8);
  bf16x8 vg0 = *(const bf16x8*)(Vh + (size_t)sr * S + g * 8);
  bf16x8 vg1 = *(const bf16x8*)(Vh + (size_t)(sr + 32) * S + g * 8);

  for (int kt = 0; kt < nT; ++kt) {
    const int kc = kt * 64;
    __syncthreads();
    *(bf16x8*)&sK[sr][g][0]      = kg0;
    *(bf16x8*)&sK[sr + 32][g][0] = kg1;
    *(bf16x8*)&sV[sr][g][0]      = vg0;
    *(bf16x8*)&sV[sr + 32][g][0] = vg1;
    __syncthreads();
    if (kt + 1 < nT) {                     // prefetch next tile into regs
      const int kn = kc + 64;
      kg0 = *(const bf16x8*)(Kh + (size_t)(kn + sr) * Dh + g * 8);
      kg1 = *(const bf16x8*)(Kh + (size_t)(kn + sr + 32) * Dh + g * 8);
      vg0 = *(const bf16x8*)(Vh + (size_t)sr * S + kn + g * 8);
      vg1 = *(const bf16x8*)(Vh + (size_t)(sr + 32) * S + kn + g * 8);
    }

    #pragma unroll
    for (int t = 0; t < 2; ++t) {
      const int cc = kc + t * 32;
      const bool act0 = cc <= r0m[0] + 15;
      const bool act1 = cc <= r0m[1] + 15;
      if (!act0 && !act1) continue;        // wave-uniform; no barriers below
      const int pb = (2 * kt + t) & 1;     // pbuf double-buffer index

      #pragma unroll
      for (int cf2 = 0; cf2 < 2; ++cf2) {
        const int c0f = cc + cf2 * 16;
        const int cl = t * 32 + cf2 * 16;  // tile-local s row base
        bf16x8 kf0 = *(const bf16x8*)&sK[cl + lrow][quad][0];
        bf16x8 kf1 = *(const bf16x8*)&sK[cl + lrow][4 + quad][0];
        const int c = c0f + lrow;
        float Cc = sth[c];
        #pragma unroll
        for (int mi = 0; mi < 2; ++mi) {
          if (!(mi ? act1 : act0)) continue;
          const int r0 = r0m[mi];
          const int prow = mi * 16 + quad * 4;
          bf16* prow_base0 = &pbuf[pb][w][prow][0][0];
          if (c0f > r0 + 15) {             // fully masked frag -> zeros
            #pragma unroll
            for (int r = 0; r < 4; ++r)
              prow_base0[r * 40 + cf2 * 16 + lrow] = (bf16)0.f;
          } else {
            floatx4 sacc = zero;
            sacc = MFMA16(qf[mi][0], kf0, sacc);
            sacc = MFMA16(qf[mi][1], kf1, sacc);
            const bool fullf = (c0f + 15 <= r0);
            #pragma unroll
            for (int r = 0; r < 4; ++r) {
              float p = exp2f(sacc[r] - Cc);
              if (!fullf) p = (c <= r0 + quad * 4 + r) ? p : 0.f;
              prow_base0[r * 40 + cf2 * 16 + lrow] = (bf16)p;
            }
          }
        }
      }

      bf16x8 vf[4];
      #pragma unroll
      for (int nf = 0; nf < 4; ++nf)
        vf[nf] = *(const bf16x8*)&sV[nf * 16 + lrow][t * 4 + quad][0];
      #pragma unroll
      for (int mi = 0; mi < 2; ++mi) {
        if (!(mi ? act1 : act0)) continue;
        bf16x8 pf = *(const bf16x8*)&pbuf[pb][w][mi * 16 + lrow][quad][0];
        #pragma unroll
        for (int nf = 0; nf < 4; ++nf)
          accO[mi][nf] = MFMA16(pf, vf[nf], accO[mi][nf]);
      }
    }
  }

  const int b = bh >> 4, h = bh & 15;
  #pragma unroll
  for (int mi = 0; mi < 2; ++mi) {
    #pragma unroll
    for (int nf = 0; nf < 4; ++nf) {
      #pragma unroll
      for (int r = 0; r < 4; ++r) {
        int qq = r0m[mi] + quad * 4 + r;
        int d = nf * 16 + lrow;
        AttOut[((size_t)(b * S + qq)) * DM + h * 64 + d] = (bf16)accO[mi][nf][r];
      }
    }
  }
}

// ---------------------------------------------------------------------------
extern "C" void kernel_launch(void* const* d_in, const int* in_sizes, int n_in,
                              void* d_out, int out_size, void* d_ws, size_t ws_size,
                              hipStream_t stream) {
  (void)in_sizes; (void)n_in; (void)out_size; (void)ws_size;
  const float* queries = (const float*)d_in[0];
  const float* keys    = (const float*)d_in[1];
  const float* values  = (const float*)d_in[2];
  const float* Wq_w = (const float*)d_in[3];  const float* Wq_b = (const float*)d_in[4];
  const float* Wk_w = (const float*)d_in[5];  const float* Wk_b = (const float*)d_in[6];
  const float* Wv_w = (const float*)d_in[7];  const float* Wv_b = (const float*)d_in[8];
  const float* Aq_w = (const float*)d_in[9];  const float* Aq_b = (const float*)d_in[10];
  const float* Bq_w = (const float*)d_in[11]; const float* Bq_b = (const float*)d_in[12];
  const float* Ak_w = (const float*)d_in[13]; const float* Ak_b = (const float*)d_in[14];
  const float* Bk_w = (const float*)d_in[15]; const float* Bk_b = (const float*)d_in[16];
  const float* Av_w = (const float*)d_in[17]; const float* Av_b = (const float*)d_in[18];
  const float* Bv_w = (const float*)d_in[19]; const float* Bv_b = (const float*)d_in[20];
  const float* Wo_w = (const float*)d_in[21]; const float* Wo_b = (const float*)d_in[22];
  float* out = (float*)d_out;

  char* ws = (char*)d_ws;
  size_t off = 0;
  auto alloc = [&](size_t bytes) -> void* {
    void* p = ws + off;
    off += (bytes + 255) & ~(size_t)255;
    return p;
  };
  bf16*  X_all  = (bf16*)alloc((size_t)8192 * 3072 * 2);
  bf16*  Qb     = (bf16*)alloc((size_t)64 * 2048 * 64 * 2);
  bf16*  Kb     = (bf16*)alloc((size_t)64 * 2048 * 64 * 2);
  bf16*  Vt     = (bf16*)alloc((size_t)64 * 64 * 2048 * 2);
  bf16*  AttOut = (bf16*)alloc((size_t)8192 * 1024 * 2);
  bf16*  WqT    = (bf16*)alloc((size_t)1024 * 1024 * 2);
  bf16*  WkT    = (bf16*)alloc((size_t)1024 * 1024 * 2);
  bf16*  WvT    = (bf16*)alloc((size_t)1024 * 2048 * 2);
  bf16*  WoT    = (bf16*)alloc((size_t)1024 * 1024 * 2);
  float* bq     = (float*)alloc(1024 * 4);
  float* bk     = (float*)alloc(1024 * 4);
  float* bv     = (float*)alloc(1024 * 4);
  float* bo     = (float*)alloc(1024 * 4);
  float* statC  = (float*)alloc((size_t)64 * 2048 * 4);

  prep_convert<<<8192, 256, 0, stream>>>(queries, keys, values, X_all);
  fold_weights<<<dim3(32, 32), dim3(32, 8), 0, stream>>>(
      Wq_w, Aq_w, Bq_w, Wk_w, Ak_w, Bk_w, Wv_w, Av_w, Bv_w, Wo_w,
      WqT, WkT, WvT, WoT);
  fold_bias<<<4, 256, 0, stream>>>(
      Wq_b, Aq_b, Bq_w, Bq_b, Wk_b, Ak_b, Bk_w, Bk_b,
      Wv_b, Av_b, Bv_w, Bv_b, Wo_b, bq, bk, bv, bo);

  // Q gets log2e folded in (scores land in log2 domain for exp2-only softmax)
  gemm_bf16<<<dim3(8, 64), 256, 0, stream>>>(X_all,        3072, WqT, bq, 8192, 1024, 1024, LOG2E, nullptr, Qb, 1);
  gemm_bf16<<<dim3(8, 64), 256, 0, stream>>>(X_all + 2048, 3072, WkT, bk, 8192, 1024, 1024, 1.0f,  nullptr, Kb, 1);
  gemm_bf16<<<dim3(8, 64), 256, 0, stream>>>(X_all + 1024, 3072, WvT, bv, 8192, 1024, 2048, 1.0f,  nullptr, Vt, 2);

  attn_pass1<<<dim3(16, 64), 256, 0, stream>>>(Qb, Kb, statC);
  attn_pass2<<<dim3(16, 64), 256, 0, stream>>>(Qb, Kb, Vt, statC, AttOut);

  gemm_bf16<<<dim3(8, 64), 256, 0, stream>>>(AttOut, 1024, WoT, bo, 8192, 1024, 1024, 1.0f, out, nullptr, 0);
}

// Round 5
// 480.261 us; speedup vs baseline: 1.9251x; 1.1036x over previous
//
#include <hip/hip_runtime.h>
#include <math.h>
#include <stdint.h>

typedef __bf16 bf16;
typedef __bf16 bf16x8 __attribute__((ext_vector_type(8)));
typedef __bf16 bf16x4 __attribute__((ext_vector_type(4)));
typedef float  floatx4 __attribute__((ext_vector_type(4)));

#define MFMA16(a, b, c) __builtin_amdgcn_mfma_f32_16x16x32_bf16(a, b, c, 0, 0, 0)
#define EXP2(x) __builtin_amdgcn_exp2f(x)

static constexpr int S  = 2048;
static constexpr int DM = 1024;
static constexpr int Dh = 64;
#define NEGBIG (-1e30f)
#define LOG2E  1.44269504088896340736f

// async global->LDS, 16B per lane; LDS dest = wave-uniform base + lane*16
__device__ __forceinline__ void gload16(const void* g, void* l) {
  __builtin_amdgcn_global_load_lds(
      (const __attribute__((address_space(1))) void*)(uintptr_t)g,
      (__attribute__((address_space(3))) void*)(uintptr_t)l,
      16, 0, 0);
}

// ---------------------------------------------------------------------------
// Pack queries|values|keys into one bf16 [8192][3072] buffer (X_all).
// ---------------------------------------------------------------------------
__global__ __launch_bounds__(256) void prep_convert(
    const float* __restrict__ q, const float* __restrict__ k,
    const float* __restrict__ v, bf16* __restrict__ X)
{
  int s = blockIdx.x;
  int c = threadIdx.x * 4;
  size_t src = (size_t)s * DM + c;
  float4 qv = *(const float4*)(q + src);
  float4 vv = *(const float4*)(v + src);
  float4 kv = *(const float4*)(k + src);
  size_t dst = (size_t)s * (3 * DM);
  bf16x4 t;
  t[0] = (bf16)qv.x; t[1] = (bf16)qv.y; t[2] = (bf16)qv.z; t[3] = (bf16)qv.w;
  *(bf16x4*)(X + dst + c) = t;
  t[0] = (bf16)vv.x; t[1] = (bf16)vv.y; t[2] = (bf16)vv.z; t[3] = (bf16)vv.w;
  *(bf16x4*)(X + dst + DM + c) = t;
  t[0] = (bf16)kv.x; t[1] = (bf16)kv.y; t[2] = (bf16)kv.z; t[3] = (bf16)kv.w;
  *(bf16x4*)(X + dst + 2 * DM + c) = t;
}

// ---------------------------------------------------------------------------
// Fold LoRA into effective weights (transposed bf16 for GEMM B-operand).
// ---------------------------------------------------------------------------
__global__ __launch_bounds__(256) void fold_weights(
    const float* __restrict__ Wq, const float* __restrict__ Aq, const float* __restrict__ Bq,
    const float* __restrict__ Wk, const float* __restrict__ Ak, const float* __restrict__ Bk,
    const float* __restrict__ Wv, const float* __restrict__ Av, const float* __restrict__ Bv,
    const float* __restrict__ Wo,
    bf16* __restrict__ WqT, bf16* __restrict__ WkT,
    bf16* __restrict__ WvT, bf16* __restrict__ WoT)
{
  __shared__ float tile[32][33];
  const int tx = threadIdx.x, ty = threadIdx.y;  // block (32, 8)
  const int n0 = blockIdx.x * 32, k0 = blockIdx.y * 32;
  for (int mi = 0; mi < 5; ++mi) {
    #pragma unroll
    for (int i = 0; i < 4; ++i) {
      int k = k0 + ty + i * 8, n = n0 + tx;
      float val = 0.f;
      if (mi == 0) {
        val = Wq[(size_t)k * DM + n];
        #pragma unroll
        for (int r = 0; r < 8; ++r) val += Aq[k * 8 + r] * Bq[(size_t)r * DM + n];
      } else if (mi == 1) {
        val = Wk[(size_t)k * DM + n];
        #pragma unroll
        for (int r = 0; r < 8; ++r) val += Ak[k * 8 + r] * Bk[(size_t)r * DM + n];
      } else if (mi == 2) {
        val = Wv[(size_t)k * DM + n];
      } else if (mi == 3) {
        #pragma unroll
        for (int r = 0; r < 8; ++r) val += Av[k * 8 + r] * Bv[(size_t)r * DM + n];
      } else {
        val = Wo[(size_t)k * DM + n];
      }
      tile[ty + i * 8][tx] = val;
    }
    __syncthreads();
    #pragma unroll
    for (int i = 0; i < 4; ++i) {
      int n = n0 + ty + i * 8, k = k0 + tx;
      float val = tile[tx][ty + i * 8];
      if (mi == 0)      WqT[(size_t)n * DM + k] = (bf16)val;
      else if (mi == 1) WkT[(size_t)n * DM + k] = (bf16)val;
      else if (mi == 2) WvT[(size_t)n * 2048 + k] = (bf16)val;
      else if (mi == 3) WvT[(size_t)n * 2048 + 1024 + k] = (bf16)val;
      else              WoT[(size_t)n * DM + k] = (bf16)val;
    }
    __syncthreads();
  }
}

__global__ __launch_bounds__(256) void fold_bias(
    const float* __restrict__ Wqb, const float* __restrict__ Aqb,
    const float* __restrict__ BqW, const float* __restrict__ Bqb,
    const float* __restrict__ Wkb, const float* __restrict__ Akb,
    const float* __restrict__ BkW, const float* __restrict__ Bkb,
    const float* __restrict__ Wvb, const float* __restrict__ Avb,
    const float* __restrict__ BvW, const float* __restrict__ Bvb,
    const float* __restrict__ Wob,
    float* __restrict__ bq, float* __restrict__ bk,
    float* __restrict__ bv, float* __restrict__ bo)
{
  int n = blockIdx.x * 256 + threadIdx.x;
  float aq = Wqb[n] + Bqb[n];
  float ak = Wkb[n] + Bkb[n];
  float av = Wvb[n] + Bvb[n];
  #pragma unroll
  for (int r = 0; r < 8; ++r) {
    aq += Aqb[r] * BqW[(size_t)r * DM + n];
    ak += Akb[r] * BkW[(size_t)r * DM + n];
    av += Avb[r] * BvW[(size_t)r * DM + n];
  }
  bq[n] = aq; bk[n] = ak; bv[n] = av; bo[n] = Wob[n];
}

// ---------------------------------------------------------------------------
// m97-style 128x128 bf16 MFMA GEMM, global_load_lds width=16 staging.
// mode 0: fp32 [M][N] (+col bias)
// mode 1: bf16 [bh][s][d] scatter (+col bias)     (Q/K)
// mode 3: bf16 [bh][d][s] scatter (+ROW bias)     (V computed transposed:
//         A=WvT so gm=(h,d), gn=(b,s); lanes vary s -> coalesced stores)
// ---------------------------------------------------------------------------
__global__ __launch_bounds__(256) void gemm_bf16(
    const bf16* __restrict__ A, int lda,
    const bf16* __restrict__ BT, int ldb,
    const float* __restrict__ bias,
    int M, int N, int K, float oscale,
    float* __restrict__ outF, bf16* __restrict__ outB, int mode)
{
  __shared__ bf16 sA[128 * 32];
  __shared__ bf16 sB[128 * 32];
  const int tid = threadIdx.x;
  const int bm0 = blockIdx.y * 128, bn0 = blockIdx.x * 128;
  const int w = tid >> 6, lane = tid & 63, lrow = lane & 15, quad = lane >> 4;
  const int wm = (w >> 1) * 64, wn = (w & 1) * 64;

  const int srow = lane >> 2;          // 0..15
  const int scol = (lane & 3) * 8;     // bf16 elems (16B granule)
  const bf16* Ag0 = A  + (size_t)(bm0 + w * 32 + srow) * lda + scol;
  const bf16* Ag1 = A  + (size_t)(bm0 + w * 32 + 16 + srow) * lda + scol;
  const bf16* Bg0 = BT + (size_t)(bn0 + w * 32 + srow) * ldb + scol;
  const bf16* Bg1 = BT + (size_t)(bn0 + w * 32 + 16 + srow) * ldb + scol;
  bf16* sA0 = &sA[(w * 32) * 32];
  bf16* sA1 = &sA[(w * 32 + 16) * 32];
  bf16* sB0 = &sB[(w * 32) * 32];
  bf16* sB1 = &sB[(w * 32 + 16) * 32];

  floatx4 zero = {0.f, 0.f, 0.f, 0.f};
  floatx4 acc[4][4];
  #pragma unroll
  for (int i = 0; i < 4; ++i)
    #pragma unroll
    for (int j = 0; j < 4; ++j) acc[i][j] = zero;

  for (int kt = 0; kt < K; kt += 32) {
    __syncthreads();
    gload16(Ag0 + kt, sA0);
    gload16(Ag1 + kt, sA1);
    gload16(Bg0 + kt, sB0);
    gload16(Bg1 + kt, sB1);
    __syncthreads();
    bf16x8 aF[4], bF[4];
    #pragma unroll
    for (int i = 0; i < 4; ++i)
      aF[i] = *(const bf16x8*)&sA[(wm + i * 16 + lrow) * 32 + quad * 8];
    #pragma unroll
    for (int j = 0; j < 4; ++j)
      bF[j] = *(const bf16x8*)&sB[(wn + j * 16 + lrow) * 32 + quad * 8];
    #pragma unroll
    for (int i = 0; i < 4; ++i)
      #pragma unroll
      for (int j = 0; j < 4; ++j)
        acc[i][j] = MFMA16(aF[i], bF[j], acc[i][j]);
  }

  if (mode == 3) {                       // row bias, [bh][d][s] coalesced
    #pragma unroll
    for (int i = 0; i < 4; ++i) {
      #pragma unroll
      for (int r = 0; r < 4; ++r) {
        int gm = bm0 + wm + i * 16 + quad * 4 + r;   // (h,d)
        float bvr = bias[gm];
        int h = gm >> 6, d = gm & 63;
        #pragma unroll
        for (int j = 0; j < 4; ++j) {
          int gn = bn0 + wn + j * 16 + lrow;          // (b,s)
          int b = gn >> 11, s = gn & 2047;
          outB[((size_t)(b * 16 + h) * 64 + d) * 2048 + s] =
              (bf16)(acc[i][j][r] + bvr);
        }
      }
    }
    return;
  }

  float bvs[4];
  #pragma unroll
  for (int j = 0; j < 4; ++j) bvs[j] = bias[bn0 + wn + j * 16 + lrow];

  #pragma unroll
  for (int i = 0; i < 4; ++i) {
    #pragma unroll
    for (int j = 0; j < 4; ++j) {
      #pragma unroll
      for (int r = 0; r < 4; ++r) {
        int gm = bm0 + wm + i * 16 + quad * 4 + r;
        int gn = bn0 + wn + j * 16 + lrow;
        float v = (acc[i][j][r] + bvs[j]) * oscale;
        if (mode == 0) {
          outF[(size_t)gm * N + gn] = v;
        } else {
          int b = gm >> 11, s = gm & 2047, h = gn >> 6, d = gn & 63;
          outB[((size_t)(b * 16 + h) * 2048 + s) * 64 + d] = (bf16)v;
        }
      }
    }
  }
}

// ---------------------------------------------------------------------------
// Pass 1 (log2 domain; Q pre-scaled by log2e): per-column stats over q>=c.
// Emits C[c] = m + 3 + log2(sum); pass2 weight = exp2(s - C).
// Diagonal-paired strips -> constant work per block.
// ---------------------------------------------------------------------------
__global__ __launch_bounds__(256) void attn_pass1(
    const bf16* __restrict__ Qb, const bf16* __restrict__ Kb,
    float* __restrict__ statC)
{
  const int bh = blockIdx.y;
  const int x = blockIdx.x;              // 0..15
  const int q0a = x * 64, q0b = (31 - x) * 64;
  const int tid = threadIdx.x;
  const int w = tid >> 6, lane = tid & 63, lrow = lane & 15, quad = lane >> 4;
  const bf16* Qh = Qb + (size_t)bh * S * Dh;
  const bf16* Kh = Kb + (size_t)bh * S * Dh;

  int cbase[8];
  #pragma unroll
  for (int cf = 0; cf < 8; ++cf)
    cbase[cf] = (cf < 4) ? (q0a + cf * 16) : (q0b + (cf - 4) * 16);

  bf16x8 kf[8][2];
  #pragma unroll
  for (int cf = 0; cf < 8; ++cf) {
    const bf16* kp = Kh + (size_t)(cbase[cf] + lrow) * Dh + quad * 8;
    kf[cf][0] = *(const bf16x8*)kp;
    kf[cf][1] = *(const bf16x8*)(kp + 32);
  }

  float rm[8], rs[8];
  #pragma unroll
  for (int cf = 0; cf < 8; ++cf) { rm[cf] = NEGBIG; rs[cf] = 0.f; }

  const int qs = q0a + w * 16;
  const bf16* qp0 = Qh + (size_t)(qs + lrow) * Dh + quad * 8;
  bf16x8 a0 = *(const bf16x8*)qp0, a1 = *(const bf16x8*)(qp0 + 32);

  for (int q0 = qs; q0 < S; q0 += 64) {
    bf16x8 n0 = a0, n1 = a1;
    if (q0 + 64 < S) {
      const bf16* np = Qh + (size_t)(q0 + 64 + lrow) * Dh + quad * 8;
      n0 = *(const bf16x8*)np; n1 = *(const bf16x8*)(np + 32);
    }
    #pragma unroll
    for (int cf = 0; cf < 8; ++cf) {
      const int c0f = cbase[cf];
      if (c0f > q0 + 15) continue;          // frag fully masked (uniform)
      floatx4 sacc = {0.f, 0.f, 0.f, 0.f};
      sacc = MFMA16(a0, kf[cf][0], sacc);
      sacc = MFMA16(a1, kf[cf][1], sacc);
      float v0 = sacc[0], v1 = sacc[1], v2 = sacc[2], v3 = sacc[3];
      if (q0 < c0f + 15) {                  // partially masked frag
        int c = c0f + lrow, qb = q0 + quad * 4;
        v0 = (qb + 0 >= c) ? v0 : NEGBIG;
        v1 = (qb + 1 >= c) ? v1 : NEGBIG;
        v2 = (qb + 2 >= c) ? v2 : NEGBIG;
        v3 = (qb + 3 >= c) ? v3 : NEGBIG;
      }
      float mt = fmaxf(fmaxf(v0, v1), fmaxf(v2, v3));
      float nm = fmaxf(rm[cf], mt);
      rs[cf] = rs[cf] * EXP2(rm[cf] - nm)
             + EXP2(v0 - nm) + EXP2(v1 - nm)
             + EXP2(v2 - nm) + EXP2(v3 - nm);
      rm[cf] = nm;
    }
    a0 = n0; a1 = n1;
  }

  #pragma unroll
  for (int cf = 0; cf < 8; ++cf) {
    #pragma unroll
    for (int off = 16; off < 64; off <<= 1) {
      float om = __shfl_xor(rm[cf], off, 64);
      float os = __shfl_xor(rs[cf], off, 64);
      float nm = fmaxf(rm[cf], om);
      rs[cf] = rs[cf] * EXP2(rm[cf] - nm) + os * EXP2(om - nm);
      rm[cf] = nm;
    }
  }

  __shared__ float smm[4][128];
  __shared__ float sms[4][128];
  if (quad == 0) {
    #pragma unroll
    for (int cf = 0; cf < 8; ++cf) {
      smm[w][cf * 16 + lrow] = rm[cf];
      sms[w][cf * 16 + lrow] = rs[cf];
    }
  }
  __syncthreads();
  if (tid < 128) {
    float m = smm[0][tid], sum = sms[0][tid];
    #pragma unroll
    for (int ww = 1; ww < 4; ++ww) {
      float om = smm[ww][tid], os = sms[ww][tid];
      float nm = fmaxf(m, om);
      sum = sum * EXP2(m - nm) + os * EXP2(om - nm);
      m = nm;
    }
    int col = (tid < 64) ? (q0a + tid) : (q0b + tid - 64);
    statC[(size_t)bh * S + col] = m + 3.0f + __log2f(sum);
  }
}

// ---------------------------------------------------------------------------
// Pass 2: out[q,:] = sum_{k<=q} exp2(s[q,k] - C[k]) * V[k,:]
// Diagonal-paired strips; K/V in 144B-row granule LDS; statC prefetched
// per-tile into a VGPR and extracted via __shfl (no global load in the
// critical path). Full-64-col phases: QK+exp for the whole tile, then PV
// (K=32 x 2 halves). pbuf per-wave, single-buffered (in-order DS => WAR
// within a wave is safe), 144B rows.
// ---------------------------------------------------------------------------
__global__ __launch_bounds__(256) void attn_pass2(
    const bf16* __restrict__ Qb, const bf16* __restrict__ Kb,
    const bf16* __restrict__ Vt, const float* __restrict__ statC,
    bf16* __restrict__ AttOut)
{
  const int bh = blockIdx.y;
  const int x = blockIdx.x;              // 0..15
  const int q0a = x * 64, q0b = (31 - x) * 64;
  const int tid = threadIdx.x;
  const int w = tid >> 6, lane = tid & 63, lrow = lane & 15, quad = lane >> 4;
  const bf16* Qh = Qb + (size_t)bh * S * Dh;
  const bf16* Kh = Kb + (size_t)bh * S * Dh;
  const bf16* Vh = Vt + (size_t)bh * Dh * S;   // [d][s]
  const float* sth = statC + (size_t)bh * S;

  __shared__ bf16 sK[64][9][8];        // [s-row][d-granule(+pad)][8]
  __shared__ bf16 sV[64][9][8];        // [d-row][s-granule(+pad)][8]
  __shared__ bf16 pbuf[4][32][9][8];   // per-wave [q-row][k-granule(+pad)][8]

  const int r0m[2] = { q0a + w * 16, q0b + w * 16 };
  bf16x8 qf[2][2];
  #pragma unroll
  for (int mi = 0; mi < 2; ++mi) {
    const bf16* qp = Qh + (size_t)(r0m[mi] + lrow) * Dh + quad * 8;
    qf[mi][0] = *(const bf16x8*)qp;
    qf[mi][1] = *(const bf16x8*)(qp + 32);
  }

  floatx4 zero = {0.f, 0.f, 0.f, 0.f};
  floatx4 accO[2][4];
  #pragma unroll
  for (int mi = 0; mi < 2; ++mi)
    #pragma unroll
    for (int nf = 0; nf < 4; ++nf) accO[mi][nf] = zero;

  const int sr = tid >> 3;        // 0..31
  const int g  = tid & 7;         // 16B granule
  const int nT = 32 - x;          // tiles of 64 cols
  bf16* const pw = &pbuf[w][0][0][0];

  // prefetch tile 0 (K, V, C)
  bf16x8 kg0 = *(const bf16x8*)(Kh + (size_t)sr * Dh + g * 8);
  bf16x8 kg1 = *(const bf16x8*)(Kh + (size_t)(sr + 32) * Dh + g * 8);
  bf16x8 vg0 = *(const bf16x8*)(Vh + (size_t)sr * S + g * 8);
  bf16x8 vg1 = *(const bf16x8*)(Vh + (size_t)(sr + 32) * S + g * 8);
  float  creg = sth[lane];

  for (int kt = 0; kt < nT; ++kt) {
    const int kc = kt * 64;
    __syncthreads();
    *(bf16x8*)&sK[sr][g][0]      = kg0;
    *(bf16x8*)&sK[sr + 32][g][0] = kg1;
    *(bf16x8*)&sV[sr][g][0]      = vg0;
    *(bf16x8*)&sV[sr + 32][g][0] = vg1;
    const float ccur = creg;
    __syncthreads();
    if (kt + 1 < nT) {                     // prefetch next tile
      const int kn = kc + 64;
      kg0 = *(const bf16x8*)(Kh + (size_t)(kn + sr) * Dh + g * 8);
      kg1 = *(const bf16x8*)(Kh + (size_t)(kn + sr + 32) * Dh + g * 8);
      vg0 = *(const bf16x8*)(Vh + (size_t)sr * S + kn + g * 8);
      vg1 = *(const bf16x8*)(Vh + (size_t)(sr + 32) * S + kn + g * 8);
      creg = sth[kn + lane];
    }

    bool actH[2][2];
    #pragma unroll
    for (int mi = 0; mi < 2; ++mi) {
      actH[mi][0] = kc      <= r0m[mi] + 15;
      actH[mi][1] = kc + 32 <= r0m[mi] + 15;
    }

    // ---- QK + exp2 phase over the full 64-col tile ----
    #pragma unroll
    for (int cf = 0; cf < 4; ++cf) {
      const int hh = cf >> 1;
      if (!actH[0][hh] && !actH[1][hh]) continue;
      const int c0f = kc + cf * 16;
      const int cl = cf * 16;
      bf16x8 kf0 = *(const bf16x8*)&sK[cl + lrow][quad][0];
      bf16x8 kf1 = *(const bf16x8*)&sK[cl + lrow][4 + quad][0];
      float Cc = __shfl(ccur, cf * 16 + lrow, 64);
      const int c = c0f + lrow;
      #pragma unroll
      for (int mi = 0; mi < 2; ++mi) {
        if (!actH[mi][hh]) continue;
        const int r0 = r0m[mi];
        const int prow = mi * 16 + quad * 4;
        if (c0f > r0 + 15) {               // fully masked frag -> zeros
          #pragma unroll
          for (int r = 0; r < 4; ++r)
            pw[(prow + r) * 72 + cf * 16 + lrow] = (bf16)0.f;
        } else {
          floatx4 sacc = zero;
          sacc = MFMA16(qf[mi][0], kf0, sacc);
          sacc = MFMA16(qf[mi][1], kf1, sacc);
          const bool fullf = (c0f + 15 <= r0);
          #pragma unroll
          for (int r = 0; r < 4; ++r) {
            float p = EXP2(sacc[r] - Cc);
            if (!fullf) p = (c <= r0 + quad * 4 + r) ? p : 0.f;
            pw[(prow + r) * 72 + cf * 16 + lrow] = (bf16)p;
          }
        }
      }
    }

    // ---- PV phase (two K=32 halves) ----
    #pragma unroll
    for (int hh = 0; hh < 2; ++hh) {
      if (!actH[0][hh] && !actH[1][hh]) continue;
      bf16x8 vf[4];
      #pragma unroll
      for (int nf = 0; nf < 4; ++nf)
        vf[nf] = *(const bf16x8*)&sV[nf * 16 + lrow][hh * 4 + quad][0];
      #pragma unroll
      for (int mi = 0; mi < 2; ++mi) {
        if (!actH[mi][hh]) continue;
        bf16x8 pf = *(const bf16x8*)&pbuf[w][mi * 16 + lrow][hh * 4 + quad][0];
        #pragma unroll
        for (int nf = 0; nf < 4; ++nf)
          accO[mi][nf] = MFMA16(pf, vf[nf], accO[mi][nf]);
      }
    }
  }

  const int b = bh >> 4, h = bh & 15;
  #pragma unroll
  for (int mi = 0; mi < 2; ++mi) {
    #pragma unroll
    for (int nf = 0; nf < 4; ++nf) {
      #pragma unroll
      for (int r = 0; r < 4; ++r) {
        int qq = r0m[mi] + quad * 4 + r;
        int d = nf * 16 + lrow;
        AttOut[((size_t)(b * S + qq)) * DM + h * 64 + d] = (bf16)accO[mi][nf][r];
      }
    }
  }
}

// ---------------------------------------------------------------------------
extern "C" void kernel_launch(void* const* d_in, const int* in_sizes, int n_in,
                              void* d_out, int out_size, void* d_ws, size_t ws_size,
                              hipStream_t stream) {
  (void)in_sizes; (void)n_in; (void)out_size; (void)ws_size;
  const float* queries = (const float*)d_in[0];
  const float* keys    = (const float*)d_in[1];
  const float* values  = (const float*)d_in[2];
  const float* Wq_w = (const float*)d_in[3];  const float* Wq_b = (const float*)d_in[4];
  const float* Wk_w = (const float*)d_in[5];  const float* Wk_b = (const float*)d_in[6];
  const float* Wv_w = (const float*)d_in[7];  const float* Wv_b = (const float*)d_in[8];
  const float* Aq_w = (const float*)d_in[9];  const float* Aq_b = (const float*)d_in[10];
  const float* Bq_w = (const float*)d_in[11]; const float* Bq_b = (const float*)d_in[12];
  const float* Ak_w = (const float*)d_in[13]; const float* Ak_b = (const float*)d_in[14];
  const float* Bk_w = (const float*)d_in[15]; const float* Bk_b = (const float*)d_in[16];
  const float* Av_w = (const float*)d_in[17]; const float* Av_b = (const float*)d_in[18];
  const float* Bv_w = (const float*)d_in[19]; const float* Bv_b = (const float*)d_in[20];
  const float* Wo_w = (const float*)d_in[21]; const float* Wo_b = (const float*)d_in[22];
  float* out = (float*)d_out;

  char* ws = (char*)d_ws;
  size_t off = 0;
  auto alloc = [&](size_t bytes) -> void* {
    void* p = ws + off;
    off += (bytes + 255) & ~(size_t)255;
    return p;
  };
  bf16*  X_all  = (bf16*)alloc((size_t)8192 * 3072 * 2);
  bf16*  Qb     = (bf16*)alloc((size_t)64 * 2048 * 64 * 2);
  bf16*  Kb     = (bf16*)alloc((size_t)64 * 2048 * 64 * 2);
  bf16*  Vt     = (bf16*)alloc((size_t)64 * 64 * 2048 * 2);
  bf16*  AttOut = (bf16*)alloc((size_t)8192 * 1024 * 2);
  bf16*  WqT    = (bf16*)alloc((size_t)1024 * 1024 * 2);
  bf16*  WkT    = (bf16*)alloc((size_t)1024 * 1024 * 2);
  bf16*  WvT    = (bf16*)alloc((size_t)1024 * 2048 * 2);
  bf16*  WoT    = (bf16*)alloc((size_t)1024 * 1024 * 2);
  float* bq     = (float*)alloc(1024 * 4);
  float* bk     = (float*)alloc(1024 * 4);
  float* bv     = (float*)alloc(1024 * 4);
  float* bo     = (float*)alloc(1024 * 4);
  float* statC  = (float*)alloc((size_t)64 * 2048 * 4);

  prep_convert<<<8192, 256, 0, stream>>>(queries, keys, values, X_all);
  fold_weights<<<dim3(32, 32), dim3(32, 8), 0, stream>>>(
      Wq_w, Aq_w, Bq_w, Wk_w, Ak_w, Bk_w, Wv_w, Av_w, Bv_w, Wo_w,
      WqT, WkT, WvT, WoT);
  fold_bias<<<4, 256, 0, stream>>>(
      Wq_b, Aq_b, Bq_w, Bq_b, Wk_b, Ak_b, Bk_w, Bk_b,
      Wv_b, Av_b, Bv_w, Bv_b, Wo_b, bq, bk, bv, bo);

  // Q gets log2e folded in (scores in log2 domain -> exp2-only softmax)
  gemm_bf16<<<dim3(8, 64), 256, 0, stream>>>(X_all,        3072, WqT, 1024, bq, 8192, 1024, 1024, LOG2E, nullptr, Qb, 1);
  gemm_bf16<<<dim3(8, 64), 256, 0, stream>>>(X_all + 2048, 3072, WkT, 1024, bk, 8192, 1024, 1024, 1.0f,  nullptr, Kb, 1);
  // V computed TRANSPOSED: Vt = WvT @ X^T  (M=1024 rows=(h,d), N=8192=(b,s))
  gemm_bf16<<<dim3(64, 8), 256, 0, stream>>>(WvT, 2048, X_all + 1024, 3072, bv, 1024, 8192, 2048, 1.0f, nullptr, Vt, 3);

  attn_pass1<<<dim3(16, 64), 256, 0, stream>>>(Qb, Kb, statC);
  attn_pass2<<<dim3(16, 64), 256, 0, stream>>>(Qb, Kb, Vt, statC, AttOut);

  gemm_bf16<<<dim3(8, 64), 256, 0, stream>>>(AttOut, 1024, WoT, 1024, bo, 8192, 1024, 1024, 1.0f, out, nullptr, 0);
}

// Round 6
// 474.315 us; speedup vs baseline: 1.9493x; 1.0125x over previous
//
#include <hip/hip_runtime.h>
#include <math.h>
#include <stdint.h>

typedef __bf16 bf16;
typedef __bf16 bf16x8 __attribute__((ext_vector_type(8)));
typedef __bf16 bf16x4 __attribute__((ext_vector_type(4)));
typedef float  floatx4 __attribute__((ext_vector_type(4)));

#define MFMA16(a, b, c) __builtin_amdgcn_mfma_f32_16x16x32_bf16(a, b, c, 0, 0, 0)
#define EXP2(x) __builtin_amdgcn_exp2f(x)

static constexpr int S  = 2048;
static constexpr int DM = 1024;
static constexpr int Dh = 64;
#define NEGBIG (-1e30f)
#define LOG2E  1.44269504088896340736f

// async global->LDS, 16B per lane; LDS dest = wave-uniform base + lane*16
__device__ __forceinline__ void gload16(const void* g, void* l) {
  __builtin_amdgcn_global_load_lds(
      (const __attribute__((address_space(1))) void*)(uintptr_t)g,
      (__attribute__((address_space(3))) void*)(uintptr_t)l,
      16, 0, 0);
}

// XOR-swizzled LDS offset: 64-elem (128B) rows, granule g (16B) xor'd by
// row&7 -> staging writes, frag reads, and b64 P-writes are all analytically
// conflict-free on the 32-bank LDS.
__device__ __forceinline__ int swz(int row, int g) {
  return row * 64 + ((g ^ (row & 7)) << 3);
}

// ---------------------------------------------------------------------------
// Pack queries|values|keys into one bf16 [8192][3072] buffer (X_all).
// ---------------------------------------------------------------------------
__global__ __launch_bounds__(256) void prep_convert(
    const float* __restrict__ q, const float* __restrict__ k,
    const float* __restrict__ v, bf16* __restrict__ X)
{
  int s = blockIdx.x;
  int c = threadIdx.x * 4;
  size_t src = (size_t)s * DM + c;
  float4 qv = *(const float4*)(q + src);
  float4 vv = *(const float4*)(v + src);
  float4 kv = *(const float4*)(k + src);
  size_t dst = (size_t)s * (3 * DM);
  bf16x4 t;
  t[0] = (bf16)qv.x; t[1] = (bf16)qv.y; t[2] = (bf16)qv.z; t[3] = (bf16)qv.w;
  *(bf16x4*)(X + dst + c) = t;
  t[0] = (bf16)vv.x; t[1] = (bf16)vv.y; t[2] = (bf16)vv.z; t[3] = (bf16)vv.w;
  *(bf16x4*)(X + dst + DM + c) = t;
  t[0] = (bf16)kv.x; t[1] = (bf16)kv.y; t[2] = (bf16)kv.z; t[3] = (bf16)kv.w;
  *(bf16x4*)(X + dst + 2 * DM + c) = t;
}

// ---------------------------------------------------------------------------
// Fold LoRA into effective weights (transposed bf16 for GEMM B-operand).
// ---------------------------------------------------------------------------
__global__ __launch_bounds__(256) void fold_weights(
    const float* __restrict__ Wq, const float* __restrict__ Aq, const float* __restrict__ Bq,
    const float* __restrict__ Wk, const float* __restrict__ Ak, const float* __restrict__ Bk,
    const float* __restrict__ Wv, const float* __restrict__ Av, const float* __restrict__ Bv,
    const float* __restrict__ Wo,
    bf16* __restrict__ WqT, bf16* __restrict__ WkT,
    bf16* __restrict__ WvT, bf16* __restrict__ WoT)
{
  __shared__ float tile[32][33];
  const int tx = threadIdx.x, ty = threadIdx.y;  // block (32, 8)
  const int n0 = blockIdx.x * 32, k0 = blockIdx.y * 32;
  for (int mi = 0; mi < 5; ++mi) {
    #pragma unroll
    for (int i = 0; i < 4; ++i) {
      int k = k0 + ty + i * 8, n = n0 + tx;
      float val = 0.f;
      if (mi == 0) {
        val = Wq[(size_t)k * DM + n];
        #pragma unroll
        for (int r = 0; r < 8; ++r) val += Aq[k * 8 + r] * Bq[(size_t)r * DM + n];
      } else if (mi == 1) {
        val = Wk[(size_t)k * DM + n];
        #pragma unroll
        for (int r = 0; r < 8; ++r) val += Ak[k * 8 + r] * Bk[(size_t)r * DM + n];
      } else if (mi == 2) {
        val = Wv[(size_t)k * DM + n];
      } else if (mi == 3) {
        #pragma unroll
        for (int r = 0; r < 8; ++r) val += Av[k * 8 + r] * Bv[(size_t)r * DM + n];
      } else {
        val = Wo[(size_t)k * DM + n];
      }
      tile[ty + i * 8][tx] = val;
    }
    __syncthreads();
    #pragma unroll
    for (int i = 0; i < 4; ++i) {
      int n = n0 + ty + i * 8, k = k0 + tx;
      float val = tile[tx][ty + i * 8];
      if (mi == 0)      WqT[(size_t)n * DM + k] = (bf16)val;
      else if (mi == 1) WkT[(size_t)n * DM + k] = (bf16)val;
      else if (mi == 2) WvT[(size_t)n * 2048 + k] = (bf16)val;
      else if (mi == 3) WvT[(size_t)n * 2048 + 1024 + k] = (bf16)val;
      else              WoT[(size_t)n * DM + k] = (bf16)val;
    }
    __syncthreads();
  }
}

__global__ __launch_bounds__(256) void fold_bias(
    const float* __restrict__ Wqb, const float* __restrict__ Aqb,
    const float* __restrict__ BqW, const float* __restrict__ Bqb,
    const float* __restrict__ Wkb, const float* __restrict__ Akb,
    const float* __restrict__ BkW, const float* __restrict__ Bkb,
    const float* __restrict__ Wvb, const float* __restrict__ Avb,
    const float* __restrict__ BvW, const float* __restrict__ Bvb,
    const float* __restrict__ Wob,
    float* __restrict__ bq, float* __restrict__ bk,
    float* __restrict__ bv, float* __restrict__ bo)
{
  int n = blockIdx.x * 256 + threadIdx.x;
  float aq = Wqb[n] + Bqb[n];
  float ak = Wkb[n] + Bkb[n];
  float av = Wvb[n] + Bvb[n];
  #pragma unroll
  for (int r = 0; r < 8; ++r) {
    aq += Aqb[r] * BqW[(size_t)r * DM + n];
    ak += Akb[r] * BkW[(size_t)r * DM + n];
    av += Avb[r] * BvW[(size_t)r * DM + n];
  }
  bq[n] = aq; bk[n] = ak; bv[n] = av; bo[n] = Wob[n];
}

// ---------------------------------------------------------------------------
// m97-style 128x128 bf16 MFMA GEMM, global_load_lds width=16 staging.
// mode 0: fp32 [M][N] (+col bias)
// mode 1: bf16 [bh][s][d] scatter (+col bias)     (Q/K)
// mode 3: bf16 [bh][d][s] scatter (+ROW bias)     (V computed transposed)
// ---------------------------------------------------------------------------
__global__ __launch_bounds__(256) void gemm_bf16(
    const bf16* __restrict__ A, int lda,
    const bf16* __restrict__ BT, int ldb,
    const float* __restrict__ bias,
    int M, int N, int K, float oscale,
    float* __restrict__ outF, bf16* __restrict__ outB, int mode)
{
  __shared__ bf16 sA[128 * 32];
  __shared__ bf16 sB[128 * 32];
  const int tid = threadIdx.x;
  const int bm0 = blockIdx.y * 128, bn0 = blockIdx.x * 128;
  const int w = tid >> 6, lane = tid & 63, lrow = lane & 15, quad = lane >> 4;
  const int wm = (w >> 1) * 64, wn = (w & 1) * 64;

  const int srow = lane >> 2;          // 0..15
  const int scol = (lane & 3) * 8;     // bf16 elems (16B granule)
  const bf16* Ag0 = A  + (size_t)(bm0 + w * 32 + srow) * lda + scol;
  const bf16* Ag1 = A  + (size_t)(bm0 + w * 32 + 16 + srow) * lda + scol;
  const bf16* Bg0 = BT + (size_t)(bn0 + w * 32 + srow) * ldb + scol;
  const bf16* Bg1 = BT + (size_t)(bn0 + w * 32 + 16 + srow) * ldb + scol;
  bf16* sA0 = &sA[(w * 32) * 32];
  bf16* sA1 = &sA[(w * 32 + 16) * 32];
  bf16* sB0 = &sB[(w * 32) * 32];
  bf16* sB1 = &sB[(w * 32 + 16) * 32];

  floatx4 zero = {0.f, 0.f, 0.f, 0.f};
  floatx4 acc[4][4];
  #pragma unroll
  for (int i = 0; i < 4; ++i)
    #pragma unroll
    for (int j = 0; j < 4; ++j) acc[i][j] = zero;

  for (int kt = 0; kt < K; kt += 32) {
    __syncthreads();
    gload16(Ag0 + kt, sA0);
    gload16(Ag1 + kt, sA1);
    gload16(Bg0 + kt, sB0);
    gload16(Bg1 + kt, sB1);
    __syncthreads();
    bf16x8 aF[4], bF[4];
    #pragma unroll
    for (int i = 0; i < 4; ++i)
      aF[i] = *(const bf16x8*)&sA[(wm + i * 16 + lrow) * 32 + quad * 8];
    #pragma unroll
    for (int j = 0; j < 4; ++j)
      bF[j] = *(const bf16x8*)&sB[(wn + j * 16 + lrow) * 32 + quad * 8];
    #pragma unroll
    for (int i = 0; i < 4; ++i)
      #pragma unroll
      for (int j = 0; j < 4; ++j)
        acc[i][j] = MFMA16(aF[i], bF[j], acc[i][j]);
  }

  if (mode == 3) {                       // row bias, [bh][d][s] coalesced
    #pragma unroll
    for (int i = 0; i < 4; ++i) {
      #pragma unroll
      for (int r = 0; r < 4; ++r) {
        int gm = bm0 + wm + i * 16 + quad * 4 + r;   // (h,d)
        float bvr = bias[gm];
        int h = gm >> 6, d = gm & 63;
        #pragma unroll
        for (int j = 0; j < 4; ++j) {
          int gn = bn0 + wn + j * 16 + lrow;          // (b,s)
          int b = gn >> 11, s = gn & 2047;
          outB[((size_t)(b * 16 + h) * 64 + d) * 2048 + s] =
              (bf16)(acc[i][j][r] + bvr);
        }
      }
    }
    return;
  }

  float bvs[4];
  #pragma unroll
  for (int j = 0; j < 4; ++j) bvs[j] = bias[bn0 + wn + j * 16 + lrow];

  #pragma unroll
  for (int i = 0; i < 4; ++i) {
    #pragma unroll
    for (int j = 0; j < 4; ++j) {
      #pragma unroll
      for (int r = 0; r < 4; ++r) {
        int gm = bm0 + wm + i * 16 + quad * 4 + r;
        int gn = bn0 + wn + j * 16 + lrow;
        float v = (acc[i][j][r] + bvs[j]) * oscale;
        if (mode == 0) {
          outF[(size_t)gm * N + gn] = v;
        } else {
          int b = gm >> 11, s = gm & 2047, h = gn >> 6, d = gn & 63;
          outB[((size_t)(b * 16 + h) * 2048 + s) * 64 + d] = (bf16)v;
        }
      }
    }
  }
}

// ---------------------------------------------------------------------------
// Pass 1 (log2 domain; Q pre-scaled by log2e): per-column stats over q>=c.
// Emits C[c] = m + 3 + log2(sum); pass2 weight = exp2(s - C).
// ---------------------------------------------------------------------------
__global__ __launch_bounds__(256) void attn_pass1(
    const bf16* __restrict__ Qb, const bf16* __restrict__ Kb,
    float* __restrict__ statC)
{
  const int bh = blockIdx.y;
  const int x = blockIdx.x;              // 0..15
  const int q0a = x * 64, q0b = (31 - x) * 64;
  const int tid = threadIdx.x;
  const int w = tid >> 6, lane = tid & 63, lrow = lane & 15, quad = lane >> 4;
  const bf16* Qh = Qb + (size_t)bh * S * Dh;
  const bf16* Kh = Kb + (size_t)bh * S * Dh;

  int cbase[8];
  #pragma unroll
  for (int cf = 0; cf < 8; ++cf)
    cbase[cf] = (cf < 4) ? (q0a + cf * 16) : (q0b + (cf - 4) * 16);

  bf16x8 kf[8][2];
  #pragma unroll
  for (int cf = 0; cf < 8; ++cf) {
    const bf16* kp = Kh + (size_t)(cbase[cf] + lrow) * Dh + quad * 8;
    kf[cf][0] = *(const bf16x8*)kp;
    kf[cf][1] = *(const bf16x8*)(kp + 32);
  }

  float rm[8], rs[8];
  #pragma unroll
  for (int cf = 0; cf < 8; ++cf) { rm[cf] = NEGBIG; rs[cf] = 0.f; }

  const int qs = q0a + w * 16;
  const bf16* qp0 = Qh + (size_t)(qs + lrow) * Dh + quad * 8;
  bf16x8 a0 = *(const bf16x8*)qp0, a1 = *(const bf16x8*)(qp0 + 32);

  for (int q0 = qs; q0 < S; q0 += 64) {
    bf16x8 n0 = a0, n1 = a1;
    if (q0 + 64 < S) {
      const bf16* np = Qh + (size_t)(q0 + 64 + lrow) * Dh + quad * 8;
      n0 = *(const bf16x8*)np; n1 = *(const bf16x8*)(np + 32);
    }
    #pragma unroll
    for (int cf = 0; cf < 8; ++cf) {
      const int c0f = cbase[cf];
      if (c0f > q0 + 15) continue;          // frag fully masked (uniform)
      floatx4 sacc = {0.f, 0.f, 0.f, 0.f};
      sacc = MFMA16(a0, kf[cf][0], sacc);
      sacc = MFMA16(a1, kf[cf][1], sacc);
      float v0 = sacc[0], v1 = sacc[1], v2 = sacc[2], v3 = sacc[3];
      if (q0 < c0f + 15) {                  // partially masked frag
        int c = c0f + lrow, qb = q0 + quad * 4;
        v0 = (qb + 0 >= c) ? v0 : NEGBIG;
        v1 = (qb + 1 >= c) ? v1 : NEGBIG;
        v2 = (qb + 2 >= c) ? v2 : NEGBIG;
        v3 = (qb + 3 >= c) ? v3 : NEGBIG;
      }
      float mt = fmaxf(fmaxf(v0, v1), fmaxf(v2, v3));
      float nm = fmaxf(rm[cf], mt);
      rs[cf] = rs[cf] * EXP2(rm[cf] - nm)
             + EXP2(v0 - nm) + EXP2(v1 - nm)
             + EXP2(v2 - nm) + EXP2(v3 - nm);
      rm[cf] = nm;
    }
    a0 = n0; a1 = n1;
  }

  #pragma unroll
  for (int cf = 0; cf < 8; ++cf) {
    #pragma unroll
    for (int off = 16; off < 64; off <<= 1) {
      float om = __shfl_xor(rm[cf], off, 64);
      float os = __shfl_xor(rs[cf], off, 64);
      float nm = fmaxf(rm[cf], om);
      rs[cf] = rs[cf] * EXP2(rm[cf] - nm) + os * EXP2(om - nm);
      rm[cf] = nm;
    }
  }

  __shared__ float smm[4][128];
  __shared__ float sms[4][128];
  if (quad == 0) {
    #pragma unroll
    for (int cf = 0; cf < 8; ++cf) {
      smm[w][cf * 16 + lrow] = rm[cf];
      sms[w][cf * 16 + lrow] = rs[cf];
    }
  }
  __syncthreads();
  if (tid < 128) {
    float m = smm[0][tid], sum = sms[0][tid];
    #pragma unroll
    for (int ww = 1; ww < 4; ++ww) {
      float om = smm[ww][tid], os = sms[ww][tid];
      float nm = fmaxf(m, om);
      sum = sum * EXP2(m - nm) + os * EXP2(om - nm);
      m = nm;
    }
    int col = (tid < 64) ? (q0a + tid) : (q0b + tid - 64);
    statC[(size_t)bh * S + col] = m + 3.0f + __log2f(sum);
  }
}

// ---------------------------------------------------------------------------
// Pass 2: out[q,:] = sum_{k<=q} exp2(s[q,k] - C[k]) * V[k,:]
// S^T orientation: QK MFMA as (kf, qf) -> lane holds col=q, rows=4 consecutive
// key-cols -> P written to pbuf as ONE ds_write_b64 per frag (A-layout rows
// contiguous), replacing 4 scalar b16 writes. All LDS XOR-swizzled (128B
// rows) -> conflict-free. Softmax constant C loaded as quad-uniform float4
// per cf (VMEM pipe, off the LDS critical path).
// ---------------------------------------------------------------------------
__global__ __launch_bounds__(256) void attn_pass2(
    const bf16* __restrict__ Qb, const bf16* __restrict__ Kb,
    const bf16* __restrict__ Vt, const float* __restrict__ statC,
    bf16* __restrict__ AttOut)
{
  const int bh = blockIdx.y;
  const int x = blockIdx.x;              // 0..15
  const int q0a = x * 64, q0b = (31 - x) * 64;
  const int tid = threadIdx.x;
  const int w = tid >> 6, lane = tid & 63, lrow = lane & 15, quad = lane >> 4;
  const bf16* Qh = Qb + (size_t)bh * S * Dh;
  const bf16* Kh = Kb + (size_t)bh * S * Dh;
  const bf16* Vh = Vt + (size_t)bh * Dh * S;   // [d][s]
  const float* sth = statC + (size_t)bh * S;

  __shared__ bf16 sK[64 * 64];         // [s-row][d], swizzled 128B rows
  __shared__ bf16 sV[64 * 64];         // [d-row][s], swizzled
  __shared__ bf16 pbuf[4][32 * 64];    // per-wave P [q-row][c], swizzled

  const int r0m[2] = { q0a + w * 16, q0b + w * 16 };
  bf16x8 qf[2][2];
  #pragma unroll
  for (int mi = 0; mi < 2; ++mi) {
    const bf16* qp = Qh + (size_t)(r0m[mi] + lrow) * Dh + quad * 8;
    qf[mi][0] = *(const bf16x8*)qp;
    qf[mi][1] = *(const bf16x8*)(qp + 32);
  }

  floatx4 zero = {0.f, 0.f, 0.f, 0.f};
  floatx4 accO[2][4];
  #pragma unroll
  for (int mi = 0; mi < 2; ++mi)
    #pragma unroll
    for (int nf = 0; nf < 4; ++nf) accO[mi][nf] = zero;

  const int sr = tid >> 3;        // 0..31
  const int g  = tid & 7;         // 16B granule
  const int nT = 32 - x;          // tiles of 64 cols
  bf16* const pw = &pbuf[w][0];

  // prefetch tile 0 (K, V)
  bf16x8 kg0 = *(const bf16x8*)(Kh + (size_t)sr * Dh + g * 8);
  bf16x8 kg1 = *(const bf16x8*)(Kh + (size_t)(sr + 32) * Dh + g * 8);
  bf16x8 vg0 = *(const bf16x8*)(Vh + (size_t)sr * S + g * 8);
  bf16x8 vg1 = *(const bf16x8*)(Vh + (size_t)(sr + 32) * S + g * 8);

  for (int kt = 0; kt < nT; ++kt) {
    const int kc = kt * 64;
    __syncthreads();
    *(bf16x8*)&sK[swz(sr, g)]      = kg0;
    *(bf16x8*)&sK[swz(sr + 32, g)] = kg1;
    *(bf16x8*)&sV[swz(sr, g)]      = vg0;
    *(bf16x8*)&sV[swz(sr + 32, g)] = vg1;
    // C constants for this tile: quad-uniform float4 per cf (VMEM, L1-served)
    float4 c4[4];
    #pragma unroll
    for (int cf = 0; cf < 4; ++cf)
      c4[cf] = *(const float4*)&sth[kc + cf * 16 + quad * 4];
    __syncthreads();
    if (kt + 1 < nT) {                     // prefetch next K/V tile
      const int kn = kc + 64;
      kg0 = *(const bf16x8*)(Kh + (size_t)(kn + sr) * Dh + g * 8);
      kg1 = *(const bf16x8*)(Kh + (size_t)(kn + sr + 32) * Dh + g * 8);
      vg0 = *(const bf16x8*)(Vh + (size_t)sr * S + kn + g * 8);
      vg1 = *(const bf16x8*)(Vh + (size_t)(sr + 32) * S + kn + g * 8);
    }

    bool actH[2][2];
    #pragma unroll
    for (int mi = 0; mi < 2; ++mi) {
      actH[mi][0] = kc      <= r0m[mi] + 15;
      actH[mi][1] = kc + 32 <= r0m[mi] + 15;
    }

    // ---- S^T = K·Q^T + exp2 phase (cols=q, rows=c) ----
    #pragma unroll
    for (int cf = 0; cf < 4; ++cf) {
      const int hh = cf >> 1;
      if (!actH[0][hh] && !actH[1][hh]) continue;
      const int c0f = kc + cf * 16;
      const int cl = cf * 16;
      bf16x8 kf0 = *(const bf16x8*)&sK[swz(cl + lrow, quad)];
      bf16x8 kf1 = *(const bf16x8*)&sK[swz(cl + lrow, 4 + quad)];
      const float* cc = &c4[cf].x;                 // C[c0f+quad*4+r]
      const int crb = c0f + quad * 4;              // this lane's row base (c)
      #pragma unroll
      for (int mi = 0; mi < 2; ++mi) {
        if (!actH[mi][hh]) continue;
        const int r0 = r0m[mi];
        // dest: row mi*16+lrow, cols cf*16+quad*4..+3 -> one b64
        const int gq = cf * 2 + (quad >> 1);
        const int poff = (mi * 16 + lrow) * 64 +
                         ((gq ^ (lrow & 7)) << 3) + (quad & 1) * 4;
        bf16x4 pk;
        if (c0f > r0 + 15) {               // fully masked frag
          pk[0] = pk[1] = pk[2] = pk[3] = (bf16)0.f;
        } else {
          floatx4 sacc = zero;
          sacc = MFMA16(kf0, qf[mi][0], sacc);     // A=K -> row=c, col=q
          sacc = MFMA16(kf1, qf[mi][1], sacc);
          const bool fullf = (c0f + 15 <= r0);
          const int qlane = r0 + lrow;
          #pragma unroll
          for (int r = 0; r < 4; ++r) {
            float p = EXP2(sacc[r] - cc[r]);
            if (!fullf) p = (crb + r <= qlane) ? p : 0.f;
            pk[r] = (bf16)p;
          }
        }
        *(bf16x4*)(pw + poff) = pk;
      }
    }

    // ---- PV phase (two K=32 halves) ----
    #pragma unroll
    for (int hh = 0; hh < 2; ++hh) {
      if (!actH[0][hh] && !actH[1][hh]) continue;
      bf16x8 vf[4];
      #pragma unroll
      for (int nf = 0; nf < 4; ++nf)
        vf[nf] = *(const bf16x8*)&sV[swz(nf * 16 + lrow, hh * 4 + quad)];
      #pragma unroll
      for (int mi = 0; mi < 2; ++mi) {
        if (!actH[mi][hh]) continue;
        bf16x8 pf = *(const bf16x8*)(pw + swz(mi * 16 + lrow, hh * 4 + quad));
        #pragma unroll
        for (int nf = 0; nf < 4; ++nf)
          accO[mi][nf] = MFMA16(pf, vf[nf], accO[mi][nf]);
      }
    }
  }

  const int b = bh >> 4, h = bh & 15;
  #pragma unroll
  for (int mi = 0; mi < 2; ++mi) {
    #pragma unroll
    for (int nf = 0; nf < 4; ++nf) {
      #pragma unroll
      for (int r = 0; r < 4; ++r) {
        int qq = r0m[mi] + quad * 4 + r;
        int d = nf * 16 + lrow;
        AttOut[((size_t)(b * S + qq)) * DM + h * 64 + d] = (bf16)accO[mi][nf][r];
      }
    }
  }
}

// ---------------------------------------------------------------------------
extern "C" void kernel_launch(void* const* d_in, const int* in_sizes, int n_in,
                              void* d_out, int out_size, void* d_ws, size_t ws_size,
                              hipStream_t stream) {
  (void)in_sizes; (void)n_in; (void)out_size; (void)ws_size;
  const float* queries = (const float*)d_in[0];
  const float* keys    = (const float*)d_in[1];
  const float* values  = (const float*)d_in[2];
  const float* Wq_w = (const float*)d_in[3];  const float* Wq_b = (const float*)d_in[4];
  const float* Wk_w = (const float*)d_in[5];  const float* Wk_b = (const float*)d_in[6];
  const float* Wv_w = (const float*)d_in[7];  const float* Wv_b = (const float*)d_in[8];
  const float* Aq_w = (const float*)d_in[9];  const float* Aq_b = (const float*)d_in[10];
  const float* Bq_w = (const float*)d_in[11]; const float* Bq_b = (const float*)d_in[12];
  const float* Ak_w = (const float*)d_in[13]; const float* Ak_b = (const float*)d_in[14];
  const float* Bk_w = (const float*)d_in[15]; const float* Bk_b = (const float*)d_in[16];
  const float* Av_w = (const float*)d_in[17]; const float* Av_b = (const float*)d_in[18];
  const float* Bv_w = (const float*)d_in[19]; const float* Bv_b = (const float*)d_in[20];
  const float* Wo_w = (const float*)d_in[21]; const float* Wo_b = (const float*)d_in[22];
  float* out = (float*)d_out;

  char* ws = (char*)d_ws;
  size_t off = 0;
  auto alloc = [&](size_t bytes) -> void* {
    void* p = ws + off;
    off += (bytes + 255) & ~(size_t)255;
    return p;
  };
  bf16*  X_all  = (bf16*)alloc((size_t)8192 * 3072 * 2);
  bf16*  Qb     = (bf16*)alloc((size_t)64 * 2048 * 64 * 2);
  bf16*  Kb     = (bf16*)alloc((size_t)64 * 2048 * 64 * 2);
  bf16*  Vt     = (bf16*)alloc((size_t)64 * 64 * 2048 * 2);
  bf16*  AttOut = (bf16*)alloc((size_t)8192 * 1024 * 2);
  bf16*  WqT    = (bf16*)alloc((size_t)1024 * 1024 * 2);
  bf16*  WkT    = (bf16*)alloc((size_t)1024 * 1024 * 2);
  bf16*  WvT    = (bf16*)alloc((size_t)1024 * 2048 * 2);
  bf16*  WoT    = (bf16*)alloc((size_t)1024 * 1024 * 2);
  float* bq     = (float*)alloc(1024 * 4);
  float* bk     = (float*)alloc(1024 * 4);
  float* bv     = (float*)alloc(1024 * 4);
  float* bo     = (float*)alloc(1024 * 4);
  float* statC  = (float*)alloc((size_t)64 * 2048 * 4);

  prep_convert<<<8192, 256, 0, stream>>>(queries, keys, values, X_all);
  fold_weights<<<dim3(32, 32), dim3(32, 8), 0, stream>>>(
      Wq_w, Aq_w, Bq_w, Wk_w, Ak_w, Bk_w, Wv_w, Av_w, Bv_w, Wo_w,
      WqT, WkT, WvT, WoT);
  fold_bias<<<4, 256, 0, stream>>>(
      Wq_b, Aq_b, Bq_w, Bq_b, Wk_b, Ak_b, Bk_w, Bk_b,
      Wv_b, Av_b, Bv_w, Bv_b, Wo_b, bq, bk, bv, bo);

  // Q gets log2e folded in (scores in log2 domain -> exp2-only softmax)
  gemm_bf16<<<dim3(8, 64), 256, 0, stream>>>(X_all,        3072, WqT, 1024, bq, 8192, 1024, 1024, LOG2E, nullptr, Qb, 1);
  gemm_bf16<<<dim3(8, 64), 256, 0, stream>>>(X_all + 2048, 3072, WkT, 1024, bk, 8192, 1024, 1024, 1.0f,  nullptr, Kb, 1);
  // V computed TRANSPOSED: Vt = WvT @ X^T  (M=1024 rows=(h,d), N=8192=(b,s))
  gemm_bf16<<<dim3(64, 8), 256, 0, stream>>>(WvT, 2048, X_all + 1024, 3072, bv, 1024, 8192, 2048, 1.0f, nullptr, Vt, 3);

  attn_pass1<<<dim3(16, 64), 256, 0, stream>>>(Qb, Kb, statC);
  attn_pass2<<<dim3(16, 64), 256, 0, stream>>>(Qb, Kb, Vt, statC, AttOut);

  gemm_bf16<<<dim3(8, 64), 256, 0, stream>>>(AttOut, 1024, WoT, 1024, bo, 8192, 1024, 1024, 1.0f, out, nullptr, 0);
}